// Round 1
// baseline (2661.182 us; speedup 1.0000x reference)
//
#include <hip/hip_runtime.h>
#include <math.h>

#define BATCH 16
#define CH 384
#define HH 28
#define WW 28
#define NTOK 784       // 28*28
#define NHEADS 8
#define HDIM 48
#define C4 1536
#define BN_EPS 1e-5f
#define ROWS 16
#define VT 128

// ---------------- fold BN2 into ffn1 (wscale per input channel, folded bias) --
__global__ __launch_bounds__(256) void fold_kernel(
    const float* __restrict__ ffn1_w, const float* __restrict__ ffn1_b,
    const float* __restrict__ g, const float* __restrict__ bb,
    const float* __restrict__ m, const float* __restrict__ v,
    float* __restrict__ wscale, float* __restrict__ fb) {
  int o = blockIdx.x * blockDim.x + threadIdx.x;
  if (o < CH) {
    wscale[o] = g[o] * rsqrtf(v[o] + BN_EPS);
  }
  if (o < C4) {
    float acc = ffn1_b[o];
    for (int c = 0; c < CH; ++c) {
      float s = g[c] * rsqrtf(v[c] + BN_EPS);
      float t = bb[c] - m[c] * s;
      acc += ffn1_w[(size_t)o * CH + c] * t;
    }
    fb[o] = acc;
  }
}

// ---------------- depthwise 3x3 conv + bias + BN1 (folded) -------------------
__global__ __launch_bounds__(256) void dwconv_bn(
    const float* __restrict__ x, const float* __restrict__ w,
    const float* __restrict__ cb, const float* __restrict__ g,
    const float* __restrict__ bnb, const float* __restrict__ m,
    const float* __restrict__ var, float* __restrict__ lx) {
  int bc = blockIdx.x;            // b*CH + c
  int c = bc % CH;
  const float* xp = x + (size_t)bc * NTOK;
  float* op = lx + (size_t)bc * NTOK;
  float k[9];
#pragma unroll
  for (int i = 0; i < 9; ++i) k[i] = w[c * 9 + i];
  float s = g[c] * rsqrtf(var[c] + BN_EPS);
  float sh = (cb[c] - m[c]) * s + bnb[c];
  for (int n = threadIdx.x; n < NTOK; n += 256) {
    int y = n / WW, xx = n - y * WW;
    float acc = 0.f;
#pragma unroll
    for (int ky = -1; ky <= 1; ++ky) {
      int yy = y + ky;
      if (yy < 0 || yy >= HH) continue;
#pragma unroll
      for (int kx = -1; kx <= 1; ++kx) {
        int x2 = xx + kx;
        if (x2 < 0 || x2 >= WW) continue;
        acc += k[(ky + 1) * 3 + (kx + 1)] * xp[yy * WW + x2];
      }
    }
    op[n] = acc * s + sh;
  }
}

// ---------------- generic 1x1-conv GEMM: out[b,o,n] = sum_c W[o,c]*in[b,c,n] --
// optional wscale (per-c weight scaling, for BN2 fold), optional addend
// (residual, same [B,Cout,N] layout), optional exact GELU.
template <bool GELU>
__global__ __launch_bounds__(256) void conv1x1_gemm(
    const float* __restrict__ W, const float* __restrict__ in,
    const float* __restrict__ bias, const float* __restrict__ wscale,
    const float* __restrict__ addend, float* __restrict__ out,
    int Cout, int Cin) {
  __shared__ float As[16][68];
  __shared__ float Bs[16][68];
  int b = blockIdx.z;
  int bm = blockIdx.y * 64;
  int bn = blockIdx.x * 64;
  int tid = threadIdx.x;
  int r0 = (tid >> 4) << 2;
  int c0 = (tid & 15) << 2;
  float acc[4][4] = {};
  const float* inb = in + (size_t)b * Cin * NTOK;
  for (int k0 = 0; k0 < Cin; k0 += 16) {
#pragma unroll
    for (int i = 0; i < 4; ++i) {
      int e = tid + i * 256;
      int o = e >> 4;
      int kk = e & 15;
      float wv = W[(size_t)(bm + o) * Cin + k0 + kk];
      if (wscale) wv *= wscale[k0 + kk];
      As[kk][o] = wv;
    }
#pragma unroll
    for (int i = 0; i < 4; ++i) {
      int e = tid + i * 256;
      int kk = e >> 6;
      int j = e & 63;
      int n = bn + j;
      Bs[kk][j] = (n < NTOK) ? inb[(size_t)(k0 + kk) * NTOK + n] : 0.f;
    }
    __syncthreads();
#pragma unroll
    for (int kk = 0; kk < 16; ++kk) {
      float a0 = As[kk][r0 + 0], a1 = As[kk][r0 + 1];
      float a2 = As[kk][r0 + 2], a3 = As[kk][r0 + 3];
      float b0 = Bs[kk][c0 + 0], b1 = Bs[kk][c0 + 1];
      float b2 = Bs[kk][c0 + 2], b3 = Bs[kk][c0 + 3];
      acc[0][0] += a0 * b0; acc[0][1] += a0 * b1; acc[0][2] += a0 * b2; acc[0][3] += a0 * b3;
      acc[1][0] += a1 * b0; acc[1][1] += a1 * b1; acc[1][2] += a1 * b2; acc[1][3] += a1 * b3;
      acc[2][0] += a2 * b0; acc[2][1] += a2 * b1; acc[2][2] += a2 * b2; acc[2][3] += a2 * b3;
      acc[3][0] += a3 * b0; acc[3][1] += a3 * b1; acc[3][2] += a3 * b2; acc[3][3] += a3 * b3;
    }
    __syncthreads();
  }
#pragma unroll
  for (int i = 0; i < 4; ++i) {
    int o = bm + r0 + i;   // Cout is a multiple of 64 -> always valid
    float bsv = bias[o];
#pragma unroll
    for (int j = 0; j < 4; ++j) {
      int n = bn + c0 + j;
      if (n < NTOK) {
        float vv = acc[i][j] + bsv;
        if (addend) vv += addend[((size_t)b * Cout + o) * NTOK + n];
        if (GELU) vv = 0.5f * vv * (1.f + erff(vv * 0.70710678118654752f));
        out[((size_t)b * Cout + o) * NTOK + n] = vv;
      }
    }
  }
}

// ---------------- attention: one block per (b, h, 16-row tile) ---------------
__global__ __launch_bounds__(256) void attention_kernel(
    const float* __restrict__ qb, const float* __restrict__ kb,
    const float* __restrict__ vb, float* __restrict__ ob) {
  __shared__ float qs[ROWS][HDIM];
  __shared__ float sl[ROWS][NTOK + 1];
  __shared__ float vs[HDIM][VT + 1];
  __shared__ float rowinv[ROWS];
  int tile = blockIdx.x;
  int h = blockIdx.y;
  int b = blockIdx.z;
  int tid = threadIdx.x;
  int r0 = tile * ROWS;
  const float scale = 0.14433756729740643f;  // 1/sqrt(48)
  const size_t base = ((size_t)b * CH + h * HDIM) * NTOK;

  // load scaled q tile
  for (int e = tid; e < ROWS * HDIM; e += 256) {
    int r = e / HDIM, d = e % HDIM;
    qs[r][d] = qb[base + (size_t)d * NTOK + (r0 + r)] * scale;
  }
  __syncthreads();

  // scores: thread owns column(s)
  for (int col = tid; col < NTOK; col += 256) {
    float kc[HDIM];
#pragma unroll
    for (int d = 0; d < HDIM; ++d) kc[d] = kb[base + (size_t)d * NTOK + col];
#pragma unroll
    for (int r = 0; r < ROWS; ++r) {
      float acc = 0.f;
#pragma unroll
      for (int d = 0; d < HDIM; ++d) acc += qs[r][d] * kc[d];
      sl[r][col] = acc;
    }
  }
  __syncthreads();

  // softmax: wave w handles rows 4w..4w+3
  int wave = tid >> 6, lane = tid & 63;
#pragma unroll
  for (int i = 0; i < 4; ++i) {
    int r = wave * 4 + i;
    float mx = -1e30f;
    for (int m = lane; m < NTOK; m += 64) mx = fmaxf(mx, sl[r][m]);
#pragma unroll
    for (int off = 32; off; off >>= 1) mx = fmaxf(mx, __shfl_xor(mx, off, 64));
    float sum = 0.f;
    for (int m = lane; m < NTOK; m += 64) {
      float e = __expf(sl[r][m] - mx);
      sl[r][m] = e;
      sum += e;
    }
#pragma unroll
    for (int off = 32; off; off >>= 1) sum += __shfl_xor(sum, off, 64);
    if (lane == 0) rowinv[r] = 1.f / sum;
  }

  // PV: 768 outputs, 3 per thread
  float acc0 = 0.f, acc1 = 0.f, acc2 = 0.f;
  int ra = tid / HDIM, da = tid % HDIM;
  int rb = (tid + 256) / HDIM, db = (tid + 256) % HDIM;
  int rc = (tid + 512) / HDIM, dc = (tid + 512) % HDIM;
  for (int m0 = 0; m0 < NTOK; m0 += VT) {
    int lim = min(VT, NTOK - m0);
    __syncthreads();  // prior reads of vs done (and sl/rowinv visible on 1st iter)
    for (int e = tid; e < HDIM * VT; e += 256) {
      int d = e / VT, m = e % VT;
      vs[d][m] = (m < lim) ? vb[base + (size_t)d * NTOK + m0 + m] : 0.f;
    }
    __syncthreads();
    for (int m = 0; m < lim; ++m) {
      acc0 += sl[ra][m0 + m] * vs[da][m];
      acc1 += sl[rb][m0 + m] * vs[db][m];
      acc2 += sl[rc][m0 + m] * vs[dc][m];
    }
  }
  ob[base + (size_t)da * NTOK + (r0 + ra)] = acc0 * rowinv[ra];
  ob[base + (size_t)db * NTOK + (r0 + rb)] = acc1 * rowinv[rb];
  ob[base + (size_t)dc * NTOK + (r0 + rc)] = acc2 * rowinv[rc];
}

// ---------------- launch -----------------------------------------------------
extern "C" void kernel_launch(void* const* d_in, const int* in_sizes, int n_in,
                              void* d_out, int out_size, void* d_ws, size_t ws_size,
                              hipStream_t stream) {
  const float* x       = (const float*)d_in[0];
  const float* local_w = (const float*)d_in[1];
  const float* local_b = (const float*)d_in[2];
  const float* bn1_g   = (const float*)d_in[3];
  const float* bn1_b   = (const float*)d_in[4];
  const float* bn1_m   = (const float*)d_in[5];
  const float* bn1_v   = (const float*)d_in[6];
  const float* q_w     = (const float*)d_in[7];
  const float* q_b     = (const float*)d_in[8];
  const float* k_w     = (const float*)d_in[9];
  const float* k_b     = (const float*)d_in[10];
  const float* v_w     = (const float*)d_in[11];
  const float* v_b     = (const float*)d_in[12];
  const float* proj_w  = (const float*)d_in[13];
  const float* proj_b  = (const float*)d_in[14];
  const float* ffn1_w  = (const float*)d_in[15];
  const float* ffn1_b  = (const float*)d_in[16];
  const float* ffn2_w  = (const float*)d_in[17];
  const float* ffn2_b  = (const float*)d_in[18];
  const float* bn2_g   = (const float*)d_in[19];
  const float* bn2_b   = (const float*)d_in[20];
  const float* bn2_m   = (const float*)d_in[21];
  const float* bn2_v   = (const float*)d_in[22];
  float* out = (float*)d_out;

  const size_t PLANE = (size_t)BATCH * CH * NTOK;  // 4,816,896 floats
  float* ws = (float*)d_ws;
  float* lx       = ws + 0 * PLANE;
  float* qbuf     = ws + 1 * PLANE;
  float* kbuf     = ws + 2 * PLANE;
  float* vbuf     = ws + 3 * PLANE;
  float* attn_out = ws + 4 * PLANE;
  float* resid    = ws + 5 * PLANE;
  float* ffn1_out = ws + 0 * PLANE;  // reuses lx/q/k/v region (exactly 4*PLANE)
  float* wscale   = ws + 6 * PLANE;
  float* fbias    = wscale + CH;

  // 1. fold BN2 into ffn1
  fold_kernel<<<dim3((C4 + 255) / 256), dim3(256), 0, stream>>>(
      ffn1_w, ffn1_b, bn2_g, bn2_b, bn2_m, bn2_v, wscale, fbias);

  // 2. depthwise conv + BN1
  dwconv_bn<<<dim3(BATCH * CH), dim3(256), 0, stream>>>(
      x, local_w, local_b, bn1_g, bn1_b, bn1_m, bn1_v, lx);

  dim3 gemm_grid((NTOK + 63) / 64, CH / 64, BATCH);
  dim3 gemm_grid4((NTOK + 63) / 64, C4 / 64, BATCH);

  // 3. q, k, v
  conv1x1_gemm<false><<<gemm_grid, dim3(256), 0, stream>>>(
      q_w, lx, q_b, nullptr, nullptr, qbuf, CH, CH);
  conv1x1_gemm<false><<<gemm_grid, dim3(256), 0, stream>>>(
      k_w, lx, k_b, nullptr, nullptr, kbuf, CH, CH);
  conv1x1_gemm<false><<<gemm_grid, dim3(256), 0, stream>>>(
      v_w, lx, v_b, nullptr, nullptr, vbuf, CH, CH);

  // 4. attention
  attention_kernel<<<dim3(NTOK / ROWS, NHEADS, BATCH), dim3(256), 0, stream>>>(
      qbuf, kbuf, vbuf, attn_out);

  // 5. proj + lx residual -> resid
  conv1x1_gemm<false><<<gemm_grid, dim3(256), 0, stream>>>(
      proj_w, attn_out, proj_b, nullptr, lx, resid, CH, CH);

  // 6. ffn1 with BN2 folded + GELU
  conv1x1_gemm<true><<<gemm_grid4, dim3(256), 0, stream>>>(
      ffn1_w, resid, fbias, wscale, nullptr, ffn1_out, C4, CH);

  // 7. ffn2 + residual -> out
  conv1x1_gemm<false><<<gemm_grid, dim3(256), 0, stream>>>(
      ffn2_w, ffn1_out, ffn2_b, nullptr, resid, out, CH, C4);
}

// Round 2
// 1462.139 us; speedup vs baseline: 1.8201x; 1.8201x over previous
//
#include <hip/hip_runtime.h>
#include <math.h>

#define BATCH 16
#define CH 384
#define HH 28
#define WW 28
#define NTOK 784       // 28*28
#define NHEADS 8
#define HDIM 48
#define C4 1536
#define BN_EPS 1e-5f
#define AROWS 64
#define AMT 64

// ---------------- fold BN2 into ffn1 (wscale per input channel, folded bias) --
__global__ __launch_bounds__(256) void fold_kernel(
    const float* __restrict__ ffn1_w, const float* __restrict__ ffn1_b,
    const float* __restrict__ g, const float* __restrict__ bb,
    const float* __restrict__ m, const float* __restrict__ v,
    float* __restrict__ wscale, float* __restrict__ fb) {
  int o = blockIdx.x * blockDim.x + threadIdx.x;
  if (o < CH) {
    wscale[o] = g[o] * rsqrtf(v[o] + BN_EPS);
  }
  if (o < C4) {
    float acc = ffn1_b[o];
    for (int c = 0; c < CH; ++c) {
      float s = g[c] * rsqrtf(v[c] + BN_EPS);
      float t = bb[c] - m[c] * s;
      acc += ffn1_w[(size_t)o * CH + c] * t;
    }
    fb[o] = acc;
  }
}

// ---------------- depthwise 3x3 conv + bias + BN1 (folded) -------------------
__global__ __launch_bounds__(256) void dwconv_bn(
    const float* __restrict__ x, const float* __restrict__ w,
    const float* __restrict__ cb, const float* __restrict__ g,
    const float* __restrict__ bnb, const float* __restrict__ m,
    const float* __restrict__ var, float* __restrict__ lx) {
  int bc = blockIdx.x;            // b*CH + c
  int c = bc % CH;
  const float* xp = x + (size_t)bc * NTOK;
  float* op = lx + (size_t)bc * NTOK;
  float k[9];
#pragma unroll
  for (int i = 0; i < 9; ++i) k[i] = w[c * 9 + i];
  float s = g[c] * rsqrtf(var[c] + BN_EPS);
  float sh = (cb[c] - m[c]) * s + bnb[c];
  for (int n = threadIdx.x; n < NTOK; n += 256) {
    int y = n / WW, xx = n - y * WW;
    float acc = 0.f;
#pragma unroll
    for (int ky = -1; ky <= 1; ++ky) {
      int yy = y + ky;
      if (yy < 0 || yy >= HH) continue;
#pragma unroll
      for (int kx = -1; kx <= 1; ++kx) {
        int x2 = xx + kx;
        if (x2 < 0 || x2 >= WW) continue;
        acc += k[(ky + 1) * 3 + (kx + 1)] * xp[yy * WW + x2];
      }
    }
    op[n] = acc * s + sh;
  }
}

// ---------------- generic 1x1-conv GEMM: out[b,o,n] = sum_c W[o,c]*in[b,c,n] --
template <bool GELU>
__global__ __launch_bounds__(256) void conv1x1_gemm(
    const float* __restrict__ W, const float* __restrict__ in,
    const float* __restrict__ bias, const float* __restrict__ wscale,
    const float* __restrict__ addend, float* __restrict__ out,
    int Cout, int Cin) {
  __shared__ __align__(16) float As[16][68];
  __shared__ __align__(16) float Bs[16][68];
  int b = blockIdx.z;
  int bm = blockIdx.y * 64;
  int bn = blockIdx.x * 64;
  int tid = threadIdx.x;
  int r0 = (tid >> 4) << 2;
  int c0 = (tid & 15) << 2;
  float acc[4][4] = {};
  const float* inb = in + (size_t)b * Cin * NTOK;
  for (int k0 = 0; k0 < Cin; k0 += 16) {
#pragma unroll
    for (int i = 0; i < 4; ++i) {
      int e = tid + i * 256;
      int o = e >> 4;
      int kk = e & 15;
      float wv = W[(size_t)(bm + o) * Cin + k0 + kk];
      if (wscale) wv *= wscale[k0 + kk];
      As[kk][o] = wv;
    }
#pragma unroll
    for (int i = 0; i < 4; ++i) {
      int e = tid + i * 256;
      int kk = e >> 6;
      int j = e & 63;
      int n = bn + j;
      Bs[kk][j] = (n < NTOK) ? inb[(size_t)(k0 + kk) * NTOK + n] : 0.f;
    }
    __syncthreads();
#pragma unroll
    for (int kk = 0; kk < 16; ++kk) {
      float4 av = *(const float4*)&As[kk][r0];
      float4 bv = *(const float4*)&Bs[kk][c0];
      acc[0][0] += av.x * bv.x; acc[0][1] += av.x * bv.y; acc[0][2] += av.x * bv.z; acc[0][3] += av.x * bv.w;
      acc[1][0] += av.y * bv.x; acc[1][1] += av.y * bv.y; acc[1][2] += av.y * bv.z; acc[1][3] += av.y * bv.w;
      acc[2][0] += av.z * bv.x; acc[2][1] += av.z * bv.y; acc[2][2] += av.z * bv.z; acc[2][3] += av.z * bv.w;
      acc[3][0] += av.w * bv.x; acc[3][1] += av.w * bv.y; acc[3][2] += av.w * bv.z; acc[3][3] += av.w * bv.w;
    }
    __syncthreads();
  }
#pragma unroll
  for (int i = 0; i < 4; ++i) {
    int o = bm + r0 + i;   // Cout is a multiple of 64 -> always valid
    float bsv = bias[o];
#pragma unroll
    for (int j = 0; j < 4; ++j) {
      int n = bn + c0 + j;
      if (n < NTOK) {
        float vv = acc[i][j] + bsv;
        if (addend) vv += addend[((size_t)b * Cout + o) * NTOK + n];
        if (GELU) vv = 0.5f * vv * (1.f + erff(vv * 0.70710678118654752f));
        out[((size_t)b * Cout + o) * NTOK + n] = vv;
      }
    }
  }
}

// ---------------- flash attention: block per (b, h, 64-row tile) -------------
// q/k/v in [B][C][N] layout (d-major per head). Online softmax over m-tiles.
__global__ __launch_bounds__(256) void attention_flash(
    const float* __restrict__ qb, const float* __restrict__ kb,
    const float* __restrict__ vb, float* __restrict__ ob) {
  __shared__ __align__(16) float qs[HDIM][AROWS + 4];   // 48 x 68, d-major
  __shared__ __align__(16) float ks[HDIM][AMT + 4];     // K tile, reused for V
  __shared__ __align__(16) float ps[AMT][AROWS + 4];    // P tile, m-major
  __shared__ float alphas[AROWS];
  __shared__ float linv[AROWS];

  int tid = threadIdx.x;
  int rt = blockIdx.x, h = blockIdx.y, b = blockIdx.z;
  int n0 = rt * AROWS;
  const size_t base = ((size_t)b * CH + h * HDIM) * NTOK;
  const float scale = 0.14433756729740643f;  // 1/sqrt(48)

  // S-phase mapping: thread (tr,tc) computes S[tr*4 .. +3][tc*4 .. +3]
  int tr = tid >> 4, tc = tid & 15;
  // PV mapping: rows pn..pn+3, dims pd..pd+2
  int pn = (tid & 15) * 4;
  int pd = (tid >> 4) * 3;

  // load q tile (pre-scaled)
  for (int e = tid; e < HDIM * AROWS; e += 256) {
    int d = e >> 6, nn = e & 63;
    int n = n0 + nn;
    qs[d][nn] = (n < NTOK) ? qb[base + (size_t)d * NTOK + n] * scale : 0.f;
  }

  float m_i[4], l_i[4];
#pragma unroll
  for (int i = 0; i < 4; ++i) { m_i[i] = -1e30f; l_i[i] = 0.f; }
  float O[4][3] = {};

  for (int m0 = 0; m0 < NTOK; m0 += AMT) {
    __syncthreads();  // prev PV reads of ks done; qs visible on first iter
    for (int e = tid; e < HDIM * AMT; e += 256) {
      int d = e >> 6, mm = e & 63;
      int m = m0 + mm;
      ks[d][mm] = (m < NTOK) ? kb[base + (size_t)d * NTOK + m] : 0.f;
    }
    __syncthreads();

    // S tile: 64x64x48, 4x4 per thread, float4 LDS reads
    float s[4][4] = {};
#pragma unroll 8
    for (int d = 0; d < HDIM; ++d) {
      float4 qf = *(const float4*)&qs[d][tr * 4];
      float4 kf = *(const float4*)&ks[d][tc * 4];
      s[0][0] += qf.x * kf.x; s[0][1] += qf.x * kf.y; s[0][2] += qf.x * kf.z; s[0][3] += qf.x * kf.w;
      s[1][0] += qf.y * kf.x; s[1][1] += qf.y * kf.y; s[1][2] += qf.y * kf.z; s[1][3] += qf.y * kf.w;
      s[2][0] += qf.z * kf.x; s[2][1] += qf.z * kf.y; s[2][2] += qf.z * kf.z; s[2][3] += qf.z * kf.w;
      s[3][0] += qf.w * kf.x; s[3][1] += qf.w * kf.y; s[3][2] += qf.w * kf.z; s[3][3] += qf.w * kf.w;
    }

    // online softmax; threads sharing a row are the 16 consecutive lanes (same tr)
    float al[4];
#pragma unroll
    for (int i = 0; i < 4; ++i) {
      float mx = fmaxf(fmaxf(s[i][0], s[i][1]), fmaxf(s[i][2], s[i][3]));
#pragma unroll
      for (int off = 1; off < 16; off <<= 1) mx = fmaxf(mx, __shfl_xor(mx, off, 16));
      float mnew = fmaxf(m_i[i], mx);
      al[i] = __expf(m_i[i] - mnew);
      m_i[i] = mnew;
      float sum = 0.f;
#pragma unroll
      for (int j = 0; j < 4; ++j) {
        int m = m0 + tc * 4 + j;
        float p = (m < NTOK) ? __expf(s[i][j] - mnew) : 0.f;
        ps[tc * 4 + j][tr * 4 + i] = p;
        sum += p;
      }
#pragma unroll
      for (int off = 1; off < 16; off <<= 1) sum += __shfl_xor(sum, off, 16);
      l_i[i] = l_i[i] * al[i] + sum;
    }
    if (tc == 0) {
#pragma unroll
      for (int i = 0; i < 4; ++i) alphas[tr * 4 + i] = al[i];
    }
    __syncthreads();  // ps/alphas written; S-phase reads of ks done

    // load V tile into ks buffer; rescale O meanwhile
    for (int e = tid; e < HDIM * AMT; e += 256) {
      int d = e >> 6, mm = e & 63;
      int m = m0 + mm;
      ks[d][mm] = (m < NTOK) ? vb[base + (size_t)d * NTOK + m] : 0.f;
    }
    {
      float a0 = alphas[pn + 0], a1 = alphas[pn + 1], a2 = alphas[pn + 2], a3 = alphas[pn + 3];
#pragma unroll
      for (int j = 0; j < 3; ++j) {
        O[0][j] *= a0; O[1][j] *= a1; O[2][j] *= a2; O[3][j] *= a3;
      }
    }
    __syncthreads();

    // PV: O[4 rows][3 dims] += P^T-slice . V
#pragma unroll 4
    for (int m = 0; m < AMT; ++m) {
      float4 pf = *(const float4*)&ps[m][pn];
      float v0 = ks[pd + 0][m], v1 = ks[pd + 1][m], v2 = ks[pd + 2][m];
      O[0][0] += pf.x * v0; O[0][1] += pf.x * v1; O[0][2] += pf.x * v2;
      O[1][0] += pf.y * v0; O[1][1] += pf.y * v1; O[1][2] += pf.y * v2;
      O[2][0] += pf.z * v0; O[2][1] += pf.z * v1; O[2][2] += pf.z * v2;
      O[3][0] += pf.w * v0; O[3][1] += pf.w * v1; O[3][2] += pf.w * v2;
    }
  }

  if (tc == 0) {
#pragma unroll
    for (int i = 0; i < 4; ++i) linv[tr * 4 + i] = 1.f / l_i[i];
  }
  __syncthreads();
#pragma unroll
  for (int i = 0; i < 4; ++i) {
    int n = n0 + pn + i;
    if (n < NTOK) {
      float li = linv[pn + i];
      ob[base + (size_t)(pd + 0) * NTOK + n] = O[i][0] * li;
      ob[base + (size_t)(pd + 1) * NTOK + n] = O[i][1] * li;
      ob[base + (size_t)(pd + 2) * NTOK + n] = O[i][2] * li;
    }
  }
}

// ---------------- launch -----------------------------------------------------
extern "C" void kernel_launch(void* const* d_in, const int* in_sizes, int n_in,
                              void* d_out, int out_size, void* d_ws, size_t ws_size,
                              hipStream_t stream) {
  const float* x       = (const float*)d_in[0];
  const float* local_w = (const float*)d_in[1];
  const float* local_b = (const float*)d_in[2];
  const float* bn1_g   = (const float*)d_in[3];
  const float* bn1_b   = (const float*)d_in[4];
  const float* bn1_m   = (const float*)d_in[5];
  const float* bn1_v   = (const float*)d_in[6];
  const float* q_w     = (const float*)d_in[7];
  const float* q_b     = (const float*)d_in[8];
  const float* k_w     = (const float*)d_in[9];
  const float* k_b     = (const float*)d_in[10];
  const float* v_w     = (const float*)d_in[11];
  const float* v_b     = (const float*)d_in[12];
  const float* proj_w  = (const float*)d_in[13];
  const float* proj_b  = (const float*)d_in[14];
  const float* ffn1_w  = (const float*)d_in[15];
  const float* ffn1_b  = (const float*)d_in[16];
  const float* ffn2_w  = (const float*)d_in[17];
  const float* ffn2_b  = (const float*)d_in[18];
  const float* bn2_g   = (const float*)d_in[19];
  const float* bn2_b   = (const float*)d_in[20];
  const float* bn2_m   = (const float*)d_in[21];
  const float* bn2_v   = (const float*)d_in[22];
  float* out = (float*)d_out;

  const size_t PLANE = (size_t)BATCH * CH * NTOK;  // 4,816,896 floats
  float* ws = (float*)d_ws;
  float* lx       = ws + 0 * PLANE;
  float* qbuf     = ws + 1 * PLANE;
  float* kbuf     = ws + 2 * PLANE;
  float* vbuf     = ws + 3 * PLANE;
  float* attn_out = ws + 4 * PLANE;
  float* resid    = ws + 5 * PLANE;
  float* ffn1_out = ws + 0 * PLANE;  // reuses lx/q/k/v region (exactly 4*PLANE)
  float* wscale   = ws + 6 * PLANE;
  float* fbias    = wscale + CH;

  fold_kernel<<<dim3((C4 + 255) / 256), dim3(256), 0, stream>>>(
      ffn1_w, ffn1_b, bn2_g, bn2_b, bn2_m, bn2_v, wscale, fbias);

  dwconv_bn<<<dim3(BATCH * CH), dim3(256), 0, stream>>>(
      x, local_w, local_b, bn1_g, bn1_b, bn1_m, bn1_v, lx);

  dim3 gemm_grid((NTOK + 63) / 64, CH / 64, BATCH);
  dim3 gemm_grid4((NTOK + 63) / 64, C4 / 64, BATCH);

  conv1x1_gemm<false><<<gemm_grid, dim3(256), 0, stream>>>(
      q_w, lx, q_b, nullptr, nullptr, qbuf, CH, CH);
  conv1x1_gemm<false><<<gemm_grid, dim3(256), 0, stream>>>(
      k_w, lx, k_b, nullptr, nullptr, kbuf, CH, CH);
  conv1x1_gemm<false><<<gemm_grid, dim3(256), 0, stream>>>(
      v_w, lx, v_b, nullptr, nullptr, vbuf, CH, CH);

  attention_flash<<<dim3((NTOK + AROWS - 1) / AROWS, NHEADS, BATCH), dim3(256), 0, stream>>>(
      qbuf, kbuf, vbuf, attn_out);

  conv1x1_gemm<false><<<gemm_grid, dim3(256), 0, stream>>>(
      proj_w, attn_out, proj_b, nullptr, lx, resid, CH, CH);

  conv1x1_gemm<true><<<gemm_grid4, dim3(256), 0, stream>>>(
      ffn1_w, resid, fbias, wscale, nullptr, ffn1_out, C4, CH);

  conv1x1_gemm<false><<<gemm_grid, dim3(256), 0, stream>>>(
      ffn2_w, ffn1_out, ffn2_b, nullptr, resid, out, CH, C4);
}

// Round 3
// 825.291 us; speedup vs baseline: 3.2245x; 1.7717x over previous
//
#include <hip/hip_runtime.h>
#include <hip/hip_bf16.h>
#include <math.h>

#define BATCH 16
#define CH 384
#define HH 28
#define WW 28
#define NTOK 784
#define NTOT (BATCH * NTOK)   // 12544 tokens, 98 tiles of 128
#define NHEADS 8
#define HDIM 48
#define C4 1536
#define QKVC 1152
#define BN_EPS 1e-5f
#define AROWS 64
#define AMT 64

typedef __attribute__((ext_vector_type(8))) short bf16x8;
typedef __attribute__((ext_vector_type(4))) float f32x4;

__device__ __forceinline__ void async16(void* lds, const void* g) {
  __builtin_amdgcn_global_load_lds(
      (const __attribute__((address_space(1))) void*)g,
      (__attribute__((address_space(3))) void*)lds, 16, 0, 0);
}
__device__ __forceinline__ float bf2f(__hip_bfloat16 v) { return __bfloat162float(v); }

// ---------------- prep: fold BN2 bias into ffn1 bias; concat qkv bias --------
__global__ __launch_bounds__(256) void prep_bias(
    const float* __restrict__ qb, const float* __restrict__ kb, const float* __restrict__ vb,
    const float* __restrict__ ffn1_w, const float* __restrict__ ffn1_b,
    const float* __restrict__ g, const float* __restrict__ bb,
    const float* __restrict__ m, const float* __restrict__ v,
    float* __restrict__ qkvb, float* __restrict__ fbias) {
  int o = blockIdx.x * 256 + threadIdx.x;
  if (o < CH) { qkvb[o] = qb[o]; qkvb[CH + o] = kb[o]; qkvb[2 * CH + o] = vb[o]; }
  if (o < C4) {
    float acc = ffn1_b[o];
    for (int c = 0; c < CH; ++c) {
      float s = g[c] * rsqrtf(v[c] + BN_EPS);
      acc += ffn1_w[(size_t)o * CH + c] * (bb[c] - m[c] * s);
    }
    fbias[o] = acc;
  }
}

// ---------------- weight converts --------------------------------------------
__global__ __launch_bounds__(256) void cvt_w(
    const float* __restrict__ src, __hip_bfloat16* __restrict__ dst, int n) {
  int i = blockIdx.x * 256 + threadIdx.x;
  if (i < n) dst[i] = __float2bfloat16(src[i]);
}
__global__ __launch_bounds__(256) void cvt_w_bnscaled(
    const float* __restrict__ src, const float* __restrict__ g,
    const float* __restrict__ v, __hip_bfloat16* __restrict__ dst) {
  int i = blockIdx.x * 256 + threadIdx.x;
  if (i < C4 * CH) {
    int c = i & (CH - 1);
    dst[i] = __float2bfloat16(src[i] * g[c] * rsqrtf(v[c] + BN_EPS));
  }
}

// ---------------- depthwise 3x3 conv + bias + BN1 (folded), channel-major ----
__global__ __launch_bounds__(256) void dwconv_bn(
    const float* __restrict__ x, const float* __restrict__ w,
    const float* __restrict__ cb, const float* __restrict__ g,
    const float* __restrict__ bnb, const float* __restrict__ m,
    const float* __restrict__ var, float* __restrict__ lx) {
  int bc = blockIdx.x;
  int c = bc % CH;
  const float* xp = x + (size_t)bc * NTOK;
  float* op = lx + (size_t)bc * NTOK;
  float k[9];
#pragma unroll
  for (int i = 0; i < 9; ++i) k[i] = w[c * 9 + i];
  float s = g[c] * rsqrtf(var[c] + BN_EPS);
  float sh = (cb[c] - m[c]) * s + bnb[c];
  for (int n = threadIdx.x; n < NTOK; n += 256) {
    int y = n / WW, xx = n - y * WW;
    float acc = 0.f;
#pragma unroll
    for (int ky = -1; ky <= 1; ++ky) {
      int yy = y + ky;
      if (yy < 0 || yy >= HH) continue;
#pragma unroll
      for (int kx = -1; kx <= 1; ++kx) {
        int x2 = xx + kx;
        if (x2 < 0 || x2 >= WW) continue;
        acc += k[(ky + 1) * 3 + (kx + 1)] * xp[yy * WW + x2];
      }
    }
    op[n] = acc * s + sh;
  }
}

// ---------------- transpose+convert: [B][C][N] f32 -> [B*N][C] bf16 ----------
__global__ __launch_bounds__(256) void transpose_cvt(
    const float* __restrict__ in, __hip_bfloat16* __restrict__ outb) {
  __shared__ float t[32][33];
  int b = blockIdx.z, c0 = blockIdx.y * 32, n0 = blockIdx.x * 32;
  int tx = threadIdx.x & 31, ty = threadIdx.x >> 5;
  for (int cc = ty; cc < 32; cc += 8) {
    int n = n0 + tx;
    t[cc][tx] = (n < NTOK) ? in[((size_t)b * CH + c0 + cc) * NTOK + n] : 0.f;
  }
  __syncthreads();
  for (int nn = ty; nn < 32; nn += 8) {
    int n = n0 + nn;
    if (n < NTOK) outb[((size_t)b * NTOK + n) * CH + c0 + tx] = __float2bfloat16(t[tx][nn]);
  }
}

// ---------------- MFMA GEMM --------------------------------------------------
// Arows: [Mtot][K] bf16 (K-contig), Brows: [Ntot][K] bf16 (K-contig).
// D[m][n] = sum_k A[m][k]*B[n][k].  128x128 tile, BK=32, 4 waves x (4x4 16x16x32).
// EPI 0: out bf16 [m][NB], += bias[n]
// EPI 1: out bf16 [m][NB], += bias[n] + resid[m*NB+n]
// EPI 2: out bf16 [m][NB], += bias[n], exact GELU
// EPI 3: m=outch(384), n=token; out f32 [b][384][784], += bias[m] + resid[n*384+m]
template <int EPI>
__global__ __launch_bounds__(256) void gemm_mfma(
    const __hip_bfloat16* __restrict__ Arows, const __hip_bfloat16* __restrict__ Brows,
    const float* __restrict__ bias, const __hip_bfloat16* __restrict__ resid,
    void* __restrict__ outp, int K) {
  __shared__ ushort As[128 * 32];
  __shared__ ushort Bs[128 * 32];
  const int tid = threadIdx.x;
  const int w = tid >> 6;
  const int lane = tid & 63;
  const int quad = lane >> 4;
  const int l16 = lane & 15;
  const int m0 = blockIdx.y * 128;
  const int n0 = blockIdx.x * 128;
  const int wm = (w & 1) * 64, wn = (w >> 1) * 64;
  const int NB = gridDim.x * 128;
  const int MB = gridDim.y * 128;

  f32x4 zero = {0.f, 0.f, 0.f, 0.f};
  f32x4 acc[4][4];
#pragma unroll
  for (int i = 0; i < 4; ++i)
#pragma unroll
    for (int j = 0; j < 4; ++j) acc[i][j] = zero;

  for (int k0 = 0; k0 < K; k0 += 32) {
    __syncthreads();  // all waves done reading LDS from previous step
#pragma unroll
    for (int t = 0; t < 2; ++t) {   // A staging: this wave's 128 chunks
      int c = w * 128 + t * 64 + lane;
      int row = c >> 2;
      int sg = (c & 3) ^ ((c >> 3) & 3);     // fetch swizzled k-seg into linear slot
      async16(As + (size_t)(w * 128 + t * 64) * 8,
              Arows + (size_t)(m0 + row) * K + k0 + sg * 8);
    }
#pragma unroll
    for (int t = 0; t < 2; ++t) {   // B staging
      int c = w * 128 + t * 64 + lane;
      int row = c >> 2;
      int sg = (c & 3) ^ ((c >> 3) & 3);
      async16(Bs + (size_t)(w * 128 + t * 64) * 8,
              Brows + (size_t)(n0 + row) * K + k0 + sg * 8);
    }
    __syncthreads();  // staging complete (vmcnt drained before barrier)

    bf16x8 af[4], bf[4];
#pragma unroll
    for (int i = 0; i < 4; ++i) {
      int ra = wm + i * 16 + l16;
      int sa = quad ^ ((ra >> 1) & 3);
      af[i] = *(const bf16x8*)&As[ra * 32 + sa * 8];
      int rb = wn + i * 16 + l16;
      int sb = quad ^ ((rb >> 1) & 3);
      bf[i] = *(const bf16x8*)&Bs[rb * 32 + sb * 8];
    }
#pragma unroll
    for (int i = 0; i < 4; ++i)
#pragma unroll
      for (int j = 0; j < 4; ++j)
        acc[i][j] = __builtin_amdgcn_mfma_f32_16x16x32_bf16(af[i], bf[j], acc[i][j], 0, 0, 0);
  }

  // epilogue: D element (i,j,r): row = m0+wm+i*16+quad*4+r, col = n0+wn+j*16+l16
#pragma unroll
  for (int i = 0; i < 4; ++i) {
#pragma unroll
    for (int j = 0; j < 4; ++j) {
#pragma unroll
      for (int r = 0; r < 4; ++r) {
        int mrow = m0 + wm + i * 16 + quad * 4 + r;
        int ncol = n0 + wn + j * 16 + l16;
        float val = acc[i][j][r];
        if (EPI <= 2) {
          val += bias[ncol];
          if (EPI == 1) val += bf2f(resid[(size_t)mrow * NB + ncol]);
          if (EPI == 2) val = 0.5f * val * (1.f + erff(val * 0.70710678118654752f));
          ((__hip_bfloat16*)outp)[(size_t)mrow * NB + ncol] = __float2bfloat16(val);
        } else {
          val += bias[mrow];
          val += bf2f(resid[(size_t)ncol * MB + mrow]);
          int bq = ncol / NTOK, nn = ncol - bq * NTOK;
          ((float*)outp)[((size_t)bq * MB + mrow) * NTOK + nn] = val;
        }
      }
    }
  }
}

// ---------------- flash attention (vector fp32, bf16 token-major in/out) -----
__global__ __launch_bounds__(256) void attention_flash(
    const __hip_bfloat16* __restrict__ qkv, __hip_bfloat16* __restrict__ ob) {
  __shared__ __align__(16) float qs[HDIM][AROWS + 4];
  __shared__ __align__(16) float ks[HDIM][AMT + 4];
  __shared__ __align__(16) float ps[AMT][AROWS + 4];
  __shared__ float alphas[AROWS];
  __shared__ float linv[AROWS];

  int tid = threadIdx.x;
  int rt = blockIdx.x, h = blockIdx.y, b = blockIdx.z;
  int n0 = rt * AROWS;
  const size_t tokbase = (size_t)b * NTOK;
  const int qoff = h * HDIM, koff = CH + h * HDIM, voff = 2 * CH + h * HDIM;
  const float scale = 0.14433756729740643f;  // 1/sqrt(48)

  int tr = tid >> 4, tc = tid & 15;
  int pn = (tid & 15) * 4;
  int pd = (tid >> 4) * 3;

  for (int e = tid; e < AROWS * HDIM; e += 256) {
    int nn = e / HDIM, d = e - nn * HDIM;
    int n = n0 + nn;
    qs[d][nn] = (n < NTOK) ? bf2f(qkv[(tokbase + n) * QKVC + qoff + d]) * scale : 0.f;
  }

  float m_i[4], l_i[4];
#pragma unroll
  for (int i = 0; i < 4; ++i) { m_i[i] = -1e30f; l_i[i] = 0.f; }
  float O[4][3] = {};

  for (int m0 = 0; m0 < NTOK; m0 += AMT) {
    __syncthreads();
    for (int e = tid; e < HDIM * AMT; e += 256) {
      int mm = e / HDIM, d = e - mm * HDIM;
      int m = m0 + mm;
      ks[d][mm] = (m < NTOK) ? bf2f(qkv[(tokbase + m) * QKVC + koff + d]) : 0.f;
    }
    __syncthreads();

    float s[4][4] = {};
#pragma unroll 8
    for (int d = 0; d < HDIM; ++d) {
      float4 qf = *(const float4*)&qs[d][tr * 4];
      float4 kf = *(const float4*)&ks[d][tc * 4];
      s[0][0] += qf.x * kf.x; s[0][1] += qf.x * kf.y; s[0][2] += qf.x * kf.z; s[0][3] += qf.x * kf.w;
      s[1][0] += qf.y * kf.x; s[1][1] += qf.y * kf.y; s[1][2] += qf.y * kf.z; s[1][3] += qf.y * kf.w;
      s[2][0] += qf.z * kf.x; s[2][1] += qf.z * kf.y; s[2][2] += qf.z * kf.z; s[2][3] += qf.z * kf.w;
      s[3][0] += qf.w * kf.x; s[3][1] += qf.w * kf.y; s[3][2] += qf.w * kf.z; s[3][3] += qf.w * kf.w;
    }

    float al[4];
#pragma unroll
    for (int i = 0; i < 4; ++i) {
      float mx = fmaxf(fmaxf(s[i][0], s[i][1]), fmaxf(s[i][2], s[i][3]));
#pragma unroll
      for (int off = 1; off < 16; off <<= 1) mx = fmaxf(mx, __shfl_xor(mx, off, 16));
      float mnew = fmaxf(m_i[i], mx);
      al[i] = __expf(m_i[i] - mnew);
      m_i[i] = mnew;
      float sum = 0.f;
#pragma unroll
      for (int j = 0; j < 4; ++j) {
        int m = m0 + tc * 4 + j;
        float p = (m < NTOK) ? __expf(s[i][j] - mnew) : 0.f;
        ps[tc * 4 + j][tr * 4 + i] = p;
        sum += p;
      }
#pragma unroll
      for (int off = 1; off < 16; off <<= 1) sum += __shfl_xor(sum, off, 16);
      l_i[i] = l_i[i] * al[i] + sum;
    }
    if (tc == 0) {
#pragma unroll
      for (int i = 0; i < 4; ++i) alphas[tr * 4 + i] = al[i];
    }
    __syncthreads();

    for (int e = tid; e < HDIM * AMT; e += 256) {
      int mm = e / HDIM, d = e - mm * HDIM;
      int m = m0 + mm;
      ks[d][mm] = (m < NTOK) ? bf2f(qkv[(tokbase + m) * QKVC + voff + d]) : 0.f;
    }
    {
      float a0 = alphas[pn + 0], a1 = alphas[pn + 1], a2 = alphas[pn + 2], a3 = alphas[pn + 3];
#pragma unroll
      for (int j = 0; j < 3; ++j) { O[0][j] *= a0; O[1][j] *= a1; O[2][j] *= a2; O[3][j] *= a3; }
    }
    __syncthreads();

#pragma unroll 4
    for (int m = 0; m < AMT; ++m) {
      float4 pf = *(const float4*)&ps[m][pn];
      float v0 = ks[pd + 0][m], v1 = ks[pd + 1][m], v2 = ks[pd + 2][m];
      O[0][0] += pf.x * v0; O[0][1] += pf.x * v1; O[0][2] += pf.x * v2;
      O[1][0] += pf.y * v0; O[1][1] += pf.y * v1; O[1][2] += pf.y * v2;
      O[2][0] += pf.z * v0; O[2][1] += pf.z * v1; O[2][2] += pf.z * v2;
      O[3][0] += pf.w * v0; O[3][1] += pf.w * v1; O[3][2] += pf.w * v2;
    }
  }

  if (tc == 0) {
#pragma unroll
    for (int i = 0; i < 4; ++i) linv[tr * 4 + i] = 1.f / l_i[i];
  }
  __syncthreads();
#pragma unroll
  for (int i = 0; i < 4; ++i) {
    int n = n0 + pn + i;
    if (n < NTOK) {
      float li = linv[pn + i];
      ob[(tokbase + n) * CH + h * HDIM + pd + 0] = __float2bfloat16(O[i][0] * li);
      ob[(tokbase + n) * CH + h * HDIM + pd + 1] = __float2bfloat16(O[i][1] * li);
      ob[(tokbase + n) * CH + h * HDIM + pd + 2] = __float2bfloat16(O[i][2] * li);
    }
  }
}

// ---------------- launch -----------------------------------------------------
extern "C" void kernel_launch(void* const* d_in, const int* in_sizes, int n_in,
                              void* d_out, int out_size, void* d_ws, size_t ws_size,
                              hipStream_t stream) {
  const float* x       = (const float*)d_in[0];
  const float* local_w = (const float*)d_in[1];
  const float* local_b = (const float*)d_in[2];
  const float* bn1_g   = (const float*)d_in[3];
  const float* bn1_b   = (const float*)d_in[4];
  const float* bn1_m   = (const float*)d_in[5];
  const float* bn1_v   = (const float*)d_in[6];
  const float* q_w     = (const float*)d_in[7];
  const float* q_b     = (const float*)d_in[8];
  const float* k_w     = (const float*)d_in[9];
  const float* k_b     = (const float*)d_in[10];
  const float* v_w     = (const float*)d_in[11];
  const float* v_b     = (const float*)d_in[12];
  const float* proj_w  = (const float*)d_in[13];
  const float* proj_b  = (const float*)d_in[14];
  const float* ffn1_w  = (const float*)d_in[15];
  const float* ffn1_b  = (const float*)d_in[16];
  const float* ffn2_w  = (const float*)d_in[17];
  const float* ffn2_b  = (const float*)d_in[18];
  const float* bn2_g   = (const float*)d_in[19];
  const float* bn2_b   = (const float*)d_in[20];
  const float* bn2_m   = (const float*)d_in[21];
  const float* bn2_v   = (const float*)d_in[22];

  char* wsb = (char*)d_ws;
  float*          lx_cm   = (float*)(wsb + 0);
  __hip_bfloat16* gelu_a  = (__hip_bfloat16*)(wsb + 0);          // overlaps lx_cm+qkv (dead)
  __hip_bfloat16* qkv_act = (__hip_bfloat16*)(wsb + 19267584);
  __hip_bfloat16* attn_a  = (__hip_bfloat16*)(wsb + 48168960);
  __hip_bfloat16* lx_tm   = (__hip_bfloat16*)(wsb + 57802752);
  __hip_bfloat16* resid_a = (__hip_bfloat16*)(wsb + 67436544);
  __hip_bfloat16* w_qkv   = (__hip_bfloat16*)(wsb + 77070336);
  __hip_bfloat16* w_proj  = (__hip_bfloat16*)(wsb + 77955072);
  __hip_bfloat16* w_ffn1  = (__hip_bfloat16*)(wsb + 78249984);
  __hip_bfloat16* w_ffn2  = (__hip_bfloat16*)(wsb + 79429632);
  float*          b_qkv   = (float*)(wsb + 80609280);
  float*          b_ffn1  = (float*)(wsb + 80613888);

  // prep: biases + weight converts
  prep_bias<<<dim3(6), dim3(256), 0, stream>>>(
      q_b, k_b, v_b, ffn1_w, ffn1_b, bn2_g, bn2_b, bn2_m, bn2_v, b_qkv, b_ffn1);
  const int WCC = CH * CH;           // 147456
  cvt_w<<<dim3(576), dim3(256), 0, stream>>>(q_w, w_qkv, WCC);
  cvt_w<<<dim3(576), dim3(256), 0, stream>>>(k_w, w_qkv + WCC, WCC);
  cvt_w<<<dim3(576), dim3(256), 0, stream>>>(v_w, w_qkv + 2 * WCC, WCC);
  cvt_w<<<dim3(576), dim3(256), 0, stream>>>(proj_w, w_proj, WCC);
  cvt_w<<<dim3(2304), dim3(256), 0, stream>>>(ffn2_w, w_ffn2, CH * C4);
  cvt_w_bnscaled<<<dim3(2304), dim3(256), 0, stream>>>(ffn1_w, bn2_g, bn2_v, w_ffn1);

  // depthwise conv + BN1 (channel-major f32), then transpose to token-major bf16
  dwconv_bn<<<dim3(BATCH * CH), dim3(256), 0, stream>>>(
      x, local_w, local_b, bn1_g, bn1_b, bn1_m, bn1_v, lx_cm);
  transpose_cvt<<<dim3(25, 12, BATCH), dim3(256), 0, stream>>>(lx_cm, lx_tm);

  // fused QKV GEMM: [12544x384] x [1152x384]^T -> [12544x1152]
  gemm_mfma<0><<<dim3(QKVC / 128, NTOT / 128), dim3(256), 0, stream>>>(
      lx_tm, w_qkv, b_qkv, nullptr, qkv_act, CH);

  // attention
  attention_flash<<<dim3((NTOK + AROWS - 1) / AROWS, NHEADS, BATCH), dim3(256), 0, stream>>>(
      qkv_act, attn_a);

  // proj + lx residual
  gemm_mfma<1><<<dim3(CH / 128, NTOT / 128), dim3(256), 0, stream>>>(
      attn_a, w_proj, proj_b, lx_tm, resid_a, CH);

  // ffn1 (BN2 folded) + GELU
  gemm_mfma<2><<<dim3(C4 / 128, NTOT / 128), dim3(256), 0, stream>>>(
      resid_a, w_ffn1, b_ffn1, nullptr, gelu_a, CH);

  // ffn2 + residual -> fp32 channel-major output
  gemm_mfma<3><<<dim3(NTOT / 128, CH / 128), dim3(256), 0, stream>>>(
      w_ffn2, gelu_a, ffn2_b, resid_a, d_out, C4);
}

// Round 5
// 472.370 us; speedup vs baseline: 5.6337x; 1.7471x over previous
//
#include <hip/hip_runtime.h>
#include <hip/hip_bf16.h>
#include <math.h>

#define BATCH 16
#define CH 384
#define HH 28
#define WW 28
#define NTOK 784
#define NTOT (BATCH * NTOK)   // 12544 tokens, 98 tiles of 128
#define NHEADS 8
#define HDIM 48
#define C4 1536
#define QKVC 1152
#define BN_EPS 1e-5f
#define QT 64
#define KT 64

typedef __attribute__((ext_vector_type(8))) short bf16x8;
typedef __attribute__((ext_vector_type(4))) float f32x4;

__device__ __forceinline__ void async16(void* lds, const void* g) {
  __builtin_amdgcn_global_load_lds(
      (const __attribute__((address_space(1))) void*)g,
      (__attribute__((address_space(3))) void*)lds, 16, 0, 0);
}
__device__ __forceinline__ float bf2f(__hip_bfloat16 v) { return __bfloat162float(v); }
__device__ __forceinline__ ushort f2bf_bits(float f) {
  __hip_bfloat16 t = __float2bfloat16(f);
  return *reinterpret_cast<ushort*>(&t);
}

// ---------------- prep: fold BN2 bias into ffn1 bias; concat qkv bias --------
__global__ __launch_bounds__(256) void prep_bias(
    const float* __restrict__ qb, const float* __restrict__ kb, const float* __restrict__ vb,
    const float* __restrict__ ffn1_w, const float* __restrict__ ffn1_b,
    const float* __restrict__ g, const float* __restrict__ bb,
    const float* __restrict__ m, const float* __restrict__ v,
    float* __restrict__ qkvb, float* __restrict__ fbias) {
  int o = blockIdx.x * 256 + threadIdx.x;
  if (o < CH) { qkvb[o] = qb[o]; qkvb[CH + o] = kb[o]; qkvb[2 * CH + o] = vb[o]; }
  if (o < C4) {
    float acc = ffn1_b[o];
    for (int c = 0; c < CH; ++c) {
      float s = g[c] * rsqrtf(v[c] + BN_EPS);
      acc += ffn1_w[(size_t)o * CH + c] * (bb[c] - m[c] * s);
    }
    fbias[o] = acc;
  }
}

// ---------------- weight converts --------------------------------------------
__global__ __launch_bounds__(256) void cvt_w(
    const float* __restrict__ src, __hip_bfloat16* __restrict__ dst, int n) {
  int i = blockIdx.x * 256 + threadIdx.x;
  if (i < n) dst[i] = __float2bfloat16(src[i]);
}
__global__ __launch_bounds__(256) void cvt_w_bnscaled(
    const float* __restrict__ src, const float* __restrict__ g,
    const float* __restrict__ v, __hip_bfloat16* __restrict__ dst) {
  int i = blockIdx.x * 256 + threadIdx.x;
  if (i < C4 * CH) {
    int c = i & (CH - 1);
    dst[i] = __float2bfloat16(src[i] * g[c] * rsqrtf(v[c] + BN_EPS));
  }
}

// ---------------- depthwise 3x3 conv + bias + BN1 (folded), channel-major ----
__global__ __launch_bounds__(256) void dwconv_bn(
    const float* __restrict__ x, const float* __restrict__ w,
    const float* __restrict__ cb, const float* __restrict__ g,
    const float* __restrict__ bnb, const float* __restrict__ m,
    const float* __restrict__ var, float* __restrict__ lx) {
  int bc = blockIdx.x;
  int c = bc % CH;
  const float* xp = x + (size_t)bc * NTOK;
  float* op = lx + (size_t)bc * NTOK;
  float k[9];
#pragma unroll
  for (int i = 0; i < 9; ++i) k[i] = w[c * 9 + i];
  float s = g[c] * rsqrtf(var[c] + BN_EPS);
  float sh = (cb[c] - m[c]) * s + bnb[c];
  for (int n = threadIdx.x; n < NTOK; n += 256) {
    int y = n / WW, xx = n - y * WW;
    float acc = 0.f;
#pragma unroll
    for (int ky = -1; ky <= 1; ++ky) {
      int yy = y + ky;
      if (yy < 0 || yy >= HH) continue;
#pragma unroll
      for (int kx = -1; kx <= 1; ++kx) {
        int x2 = xx + kx;
        if (x2 < 0 || x2 >= WW) continue;
        acc += k[(ky + 1) * 3 + (kx + 1)] * xp[yy * WW + x2];
      }
    }
    op[n] = acc * s + sh;
  }
}

// ---------------- transpose+convert: [B][C][N] f32 -> [B*N][C] bf16 ----------
__global__ __launch_bounds__(256) void transpose_cvt(
    const float* __restrict__ in, __hip_bfloat16* __restrict__ outb) {
  __shared__ float t[32][33];
  int b = blockIdx.z, c0 = blockIdx.y * 32, n0 = blockIdx.x * 32;
  int tx = threadIdx.x & 31, ty = threadIdx.x >> 5;
  for (int cc = ty; cc < 32; cc += 8) {
    int n = n0 + tx;
    t[cc][tx] = (n < NTOK) ? in[((size_t)b * CH + c0 + cc) * NTOK + n] : 0.f;
  }
  __syncthreads();
  for (int nn = ty; nn < 32; nn += 8) {
    int n = n0 + nn;
    if (n < NTOK) outb[((size_t)b * NTOK + n) * CH + c0 + tx] = __float2bfloat16(t[tx][nn]);
  }
}

// ---------------- MFMA GEMM (unchanged from round 3) -------------------------
template <int EPI>
__global__ __launch_bounds__(256) void gemm_mfma(
    const __hip_bfloat16* __restrict__ Arows, const __hip_bfloat16* __restrict__ Brows,
    const float* __restrict__ bias, const __hip_bfloat16* __restrict__ resid,
    void* __restrict__ outp, int K) {
  __shared__ ushort As[128 * 32];
  __shared__ ushort Bs[128 * 32];
  const int tid = threadIdx.x;
  const int w = tid >> 6;
  const int lane = tid & 63;
  const int quad = lane >> 4;
  const int l16 = lane & 15;
  const int m0 = blockIdx.y * 128;
  const int n0 = blockIdx.x * 128;
  const int wm = (w & 1) * 64, wn = (w >> 1) * 64;
  const int NB = gridDim.x * 128;
  const int MB = gridDim.y * 128;

  f32x4 zero = {0.f, 0.f, 0.f, 0.f};
  f32x4 acc[4][4];
#pragma unroll
  for (int i = 0; i < 4; ++i)
#pragma unroll
    for (int j = 0; j < 4; ++j) acc[i][j] = zero;

  for (int k0 = 0; k0 < K; k0 += 32) {
    __syncthreads();
#pragma unroll
    for (int t = 0; t < 2; ++t) {
      int c = w * 128 + t * 64 + lane;
      int row = c >> 2;
      int sg = (c & 3) ^ ((c >> 3) & 3);
      async16(As + (size_t)(w * 128 + t * 64) * 8,
              Arows + (size_t)(m0 + row) * K + k0 + sg * 8);
    }
#pragma unroll
    for (int t = 0; t < 2; ++t) {
      int c = w * 128 + t * 64 + lane;
      int row = c >> 2;
      int sg = (c & 3) ^ ((c >> 3) & 3);
      async16(Bs + (size_t)(w * 128 + t * 64) * 8,
              Brows + (size_t)(n0 + row) * K + k0 + sg * 8);
    }
    __syncthreads();

    bf16x8 af[4], bf[4];
#pragma unroll
    for (int i = 0; i < 4; ++i) {
      int ra = wm + i * 16 + l16;
      int sa = quad ^ ((ra >> 1) & 3);
      af[i] = *(const bf16x8*)&As[ra * 32 + sa * 8];
      int rb = wn + i * 16 + l16;
      int sb = quad ^ ((rb >> 1) & 3);
      bf[i] = *(const bf16x8*)&Bs[rb * 32 + sb * 8];
    }
#pragma unroll
    for (int i = 0; i < 4; ++i)
#pragma unroll
      for (int j = 0; j < 4; ++j)
        acc[i][j] = __builtin_amdgcn_mfma_f32_16x16x32_bf16(af[i], bf[j], acc[i][j], 0, 0, 0);
  }

#pragma unroll
  for (int i = 0; i < 4; ++i) {
#pragma unroll
    for (int j = 0; j < 4; ++j) {
#pragma unroll
      for (int r = 0; r < 4; ++r) {
        int mrow = m0 + wm + i * 16 + quad * 4 + r;
        int ncol = n0 + wn + j * 16 + l16;
        float val = acc[i][j][r];
        if (EPI <= 2) {
          val += bias[ncol];
          if (EPI == 1) val += bf2f(resid[(size_t)mrow * NB + ncol]);
          if (EPI == 2) val = 0.5f * val * (1.f + erff(val * 0.70710678118654752f));
          ((__hip_bfloat16*)outp)[(size_t)mrow * NB + ncol] = __float2bfloat16(val);
        } else {
          val += bias[mrow];
          val += bf2f(resid[(size_t)ncol * MB + mrow]);
          int bq = ncol / NTOK, nn = ncol - bq * NTOK;
          ((float*)outp)[((size_t)bq * MB + mrow) * NTOK + nn] = val;
        }
      }
    }
  }
}

// ---------------- MFMA flash attention ---------------------------------------
// One block = 4 waves, 64-query tile of one (b,h). Each wave owns a 16-query
// strip. qkv token-major [tok][1152]: dims contiguous -> Q/K are directly
// A/B-fragment compatible (16x16x32 bf16, dims padded 48->64 with zeros).
// V transposed into LDS [dim][token] for the PV B-fragment. P goes C-layout ->
// LDS (bf16) -> A-fragment within the same wave. Online softmax per 16-row
// strip; stats reduce over l16 via 16-wide shuffles (stay in-quad).
__global__ __launch_bounds__(256) void attention_mfma(
    const __hip_bfloat16* __restrict__ qkv, __hip_bfloat16* __restrict__ ob) {
  // stride 72 bf16 = 36 words: 16 rows x 4-bank groups alias 2-way only (free)
  __shared__ ushort Qs[QT][72];
  __shared__ ushort Ks[KT][72];
  __shared__ ushort Vts[HDIM][72];
  __shared__ ushort Ps[4][16][72];

  const int tid = threadIdx.x;
  const int w = tid >> 6, lane = tid & 63;
  const int quad = lane >> 4, l16 = lane & 15;
  const int rt = blockIdx.x, h = blockIdx.y, b = blockIdx.z;
  const int n0 = rt * QT;
  const size_t tokbase = (size_t)b * NTOK;
  const int qoff = h * HDIM, koff = CH + h * HDIM, voff = 2 * CH + h * HDIM;
  const float scale = 0.14433756729740643f;  // 1/sqrt(48)
  const int wm = w * 16;

  // stage Q tile: 64 rows x 64 dims (zero-pad dims 48..63 and rows >= NTOK)
  const bf16x8 z8 = {0, 0, 0, 0, 0, 0, 0, 0};
  for (int c = tid; c < QT * 8; c += 256) {
    int row = c >> 3, hc = c & 7;
    int tok = n0 + row;
    bf16x8 v = z8;
    if (tok < NTOK && hc < 6)
      v = *(const bf16x8*)(qkv + (tokbase + tok) * QKVC + qoff + hc * 8);
    *(bf16x8*)&Qs[row][hc * 8] = v;
  }

  f32x4 o[3];
  const f32x4 zf = {0.f, 0.f, 0.f, 0.f};
#pragma unroll
  for (int t = 0; t < 3; ++t) o[t] = zf;
  float m_i[4], l_i[4];
#pragma unroll
  for (int r = 0; r < 4; ++r) { m_i[r] = -1e30f; l_i[r] = 0.f; }

  for (int m0 = 0; m0 < NTOK; m0 += KT) {
    __syncthreads();  // prior MFMA reads of Ks/Vts done; Qs visible on iter 0
    // stage K tile
    for (int c = tid; c < KT * 8; c += 256) {
      int row = c >> 3, hc = c & 7;
      int tok = m0 + row;
      bf16x8 v = z8;
      if (tok < NTOK && hc < 6)
        v = *(const bf16x8*)(qkv + (tokbase + tok) * QKVC + koff + hc * 8);
      *(bf16x8*)&Ks[row][hc * 8] = v;
    }
    // stage V transposed: Vts[dim][token]
    for (int c = tid; c < KT * HDIM; c += 256) {
      int tok = c / HDIM, d = c - tok * HDIM;
      int t2 = m0 + tok;
      ushort val = 0;
      if (t2 < NTOK) val = *(const ushort*)(qkv + (tokbase + t2) * QKVC + voff + d);
      Vts[d][tok] = val;
    }
    __syncthreads();

    // S strip: 16 x 64, K=64 (2 k-steps), 4 col-tiles
    f32x4 s[4];
#pragma unroll
    for (int j = 0; j < 4; ++j) s[j] = zf;
#pragma unroll
    for (int kk = 0; kk < 2; ++kk) {
      bf16x8 af = *(const bf16x8*)&Qs[wm + l16][kk * 32 + quad * 8];
#pragma unroll
      for (int j = 0; j < 4; ++j) {
        bf16x8 bfv = *(const bf16x8*)&Ks[j * 16 + l16][kk * 32 + quad * 8];
        s[j] = __builtin_amdgcn_mfma_f32_16x16x32_bf16(af, bfv, s[j], 0, 0, 0);
      }
    }

    // online softmax per row (rows quad*4+r of this wave's strip)
    float alpha[4];
#pragma unroll
    for (int r = 0; r < 4; ++r) {
      float sv[4];
#pragma unroll
      for (int j = 0; j < 4; ++j) {
        sv[j] = s[j][r] * scale;
        if (m0 + j * 16 + l16 >= NTOK) sv[j] = -1e30f;
      }
      float mx = fmaxf(fmaxf(sv[0], sv[1]), fmaxf(sv[2], sv[3]));
#pragma unroll
      for (int off = 1; off < 16; off <<= 1) mx = fmaxf(mx, __shfl_xor(mx, off, 16));
      float mnew = fmaxf(m_i[r], mx);
      alpha[r] = __expf(m_i[r] - mnew);
      m_i[r] = mnew;
      float sum = 0.f;
#pragma unroll
      for (int j = 0; j < 4; ++j) {
        float p = __expf(sv[j] - mnew);
        sum += p;
        Ps[w][quad * 4 + r][j * 16 + l16] = f2bf_bits(p);
      }
#pragma unroll
      for (int off = 1; off < 16; off <<= 1) sum += __shfl_xor(sum, off, 16);
      l_i[r] = l_i[r] * alpha[r] + sum;
    }
#pragma unroll
    for (int t = 0; t < 3; ++t)
#pragma unroll
      for (int r = 0; r < 4; ++r) o[t][r] *= alpha[r];

    // PV: A = P strip [16 x 64], B = Vt [48 dims x 64 tokens], 3 col-tiles
#pragma unroll
    for (int kk = 0; kk < 2; ++kk) {
      bf16x8 pf = *(const bf16x8*)&Ps[w][l16][kk * 32 + quad * 8];
#pragma unroll
      for (int t = 0; t < 3; ++t) {
        bf16x8 vf = *(const bf16x8*)&Vts[t * 16 + l16][kk * 32 + quad * 8];
        o[t] = __builtin_amdgcn_mfma_f32_16x16x32_bf16(pf, vf, o[t], 0, 0, 0);
      }
    }
  }

  // epilogue: O row = quad*4+r (query), col = t*16+l16 (dim)
#pragma unroll
  for (int t = 0; t < 3; ++t) {
#pragma unroll
    for (int r = 0; r < 4; ++r) {
      int tok = n0 + wm + quad * 4 + r;
      if (tok < NTOK)
        ob[(tokbase + tok) * CH + h * HDIM + t * 16 + l16] =
            __float2bfloat16(o[t][r] / l_i[r]);
    }
  }
}

// ---------------- launch -----------------------------------------------------
extern "C" void kernel_launch(void* const* d_in, const int* in_sizes, int n_in,
                              void* d_out, int out_size, void* d_ws, size_t ws_size,
                              hipStream_t stream) {
  const float* x       = (const float*)d_in[0];
  const float* local_w = (const float*)d_in[1];
  const float* local_b = (const float*)d_in[2];
  const float* bn1_g   = (const float*)d_in[3];
  const float* bn1_b   = (const float*)d_in[4];
  const float* bn1_m   = (const float*)d_in[5];
  const float* bn1_v   = (const float*)d_in[6];
  const float* q_w     = (const float*)d_in[7];
  const float* q_b     = (const float*)d_in[8];
  const float* k_w     = (const float*)d_in[9];
  const float* k_b     = (const float*)d_in[10];
  const float* v_w     = (const float*)d_in[11];
  const float* v_b     = (const float*)d_in[12];
  const float* proj_w  = (const float*)d_in[13];
  const float* proj_b  = (const float*)d_in[14];
  const float* ffn1_w  = (const float*)d_in[15];
  const float* ffn1_b  = (const float*)d_in[16];
  const float* ffn2_w  = (const float*)d_in[17];
  const float* ffn2_b  = (const float*)d_in[18];
  const float* bn2_g   = (const float*)d_in[19];
  const float* bn2_b   = (const float*)d_in[20];
  const float* bn2_m   = (const float*)d_in[21];
  const float* bn2_v   = (const float*)d_in[22];

  char* wsb = (char*)d_ws;
  float*          lx_cm   = (float*)(wsb + 0);
  __hip_bfloat16* gelu_a  = (__hip_bfloat16*)(wsb + 0);          // overlaps lx_cm+qkv (dead)
  __hip_bfloat16* qkv_act = (__hip_bfloat16*)(wsb + 19267584);
  __hip_bfloat16* attn_a  = (__hip_bfloat16*)(wsb + 48168960);
  __hip_bfloat16* lx_tm   = (__hip_bfloat16*)(wsb + 57802752);
  __hip_bfloat16* resid_a = (__hip_bfloat16*)(wsb + 67436544);
  __hip_bfloat16* w_qkv   = (__hip_bfloat16*)(wsb + 77070336);
  __hip_bfloat16* w_proj  = (__hip_bfloat16*)(wsb + 77955072);
  __hip_bfloat16* w_ffn1  = (__hip_bfloat16*)(wsb + 78249984);
  __hip_bfloat16* w_ffn2  = (__hip_bfloat16*)(wsb + 79429632);
  float*          b_qkv   = (float*)(wsb + 80609280);
  float*          b_ffn1  = (float*)(wsb + 80613888);

  prep_bias<<<dim3(6), dim3(256), 0, stream>>>(
      q_b, k_b, v_b, ffn1_w, ffn1_b, bn2_g, bn2_b, bn2_m, bn2_v, b_qkv, b_ffn1);
  const int WCC = CH * CH;           // 147456
  cvt_w<<<dim3(576), dim3(256), 0, stream>>>(q_w, w_qkv, WCC);
  cvt_w<<<dim3(576), dim3(256), 0, stream>>>(k_w, w_qkv + WCC, WCC);
  cvt_w<<<dim3(576), dim3(256), 0, stream>>>(v_w, w_qkv + 2 * WCC, WCC);
  cvt_w<<<dim3(576), dim3(256), 0, stream>>>(proj_w, w_proj, WCC);
  cvt_w<<<dim3(2304), dim3(256), 0, stream>>>(ffn2_w, w_ffn2, CH * C4);
  cvt_w_bnscaled<<<dim3(2304), dim3(256), 0, stream>>>(ffn1_w, bn2_g, bn2_v, w_ffn1);

  dwconv_bn<<<dim3(BATCH * CH), dim3(256), 0, stream>>>(
      x, local_w, local_b, bn1_g, bn1_b, bn1_m, bn1_v, lx_cm);
  transpose_cvt<<<dim3(25, 12, BATCH), dim3(256), 0, stream>>>(lx_cm, lx_tm);

  gemm_mfma<0><<<dim3(QKVC / 128, NTOT / 128), dim3(256), 0, stream>>>(
      lx_tm, w_qkv, b_qkv, nullptr, qkv_act, CH);

  attention_mfma<<<dim3((NTOK + QT - 1) / QT, NHEADS, BATCH), dim3(256), 0, stream>>>(
      qkv_act, attn_a);

  gemm_mfma<1><<<dim3(CH / 128, NTOT / 128), dim3(256), 0, stream>>>(
      attn_a, w_proj, proj_b, lx_tm, resid_a, CH);

  gemm_mfma<2><<<dim3(C4 / 128, NTOT / 128), dim3(256), 0, stream>>>(
      resid_a, w_ffn1, b_ffn1, nullptr, gelu_a, CH);

  gemm_mfma<3><<<dim3(NTOT / 128, CH / 128), dim3(256), 0, stream>>>(
      w_ffn2, gelu_a, ffn2_b, resid_a, d_out, C4);
}

// Round 9
// 377.913 us; speedup vs baseline: 7.0418x; 1.2499x over previous
//
#include <hip/hip_runtime.h>
#include <hip/hip_bf16.h>
#include <math.h>

#define BATCH 16
#define CH 384
#define HH 28
#define WW 28
#define NTOK 784
#define NTOT (BATCH * NTOK)   // 12544 tokens, 98 tiles of 128
#define NHEADS 8
#define HDIM 48
#define C4 1536
#define QKVC 1152
#define BN_EPS 1e-5f
#define QTL 128               // queries per attention block
#define KTL 64                // keys per attention k-tile
#define WCC (CH * CH)         // 147456
#define NW_ALL (4 * WCC + 2 * C4 * CH)
// 1/sqrt(48) * log2(e): folded into Q weights/bias so softmax uses exp2 directly
#define LAMBDA (0.14433756729740643f * 1.4426950408889634f)
// vt layout: [384 v-channels][16 batches][832 = 13*64 phi-permuted tokens]
#define VT_BSTRIDE 832
#define VT_CSTRIDE (16 * 832)

typedef __attribute__((ext_vector_type(8))) short bf16x8;
typedef __attribute__((ext_vector_type(4))) float f32x4;

__device__ __forceinline__ void async16(void* lds, const void* g) {
  __builtin_amdgcn_global_load_lds(
      (const __attribute__((address_space(1))) void*)g,
      (__attribute__((address_space(3))) void*)lds, 16, 0, 0);
}
__device__ __forceinline__ float bf2f(__hip_bfloat16 v) { return __bfloat162float(v); }
__device__ __forceinline__ ushort f2bf_bits(float f) {
  __hip_bfloat16 t = __float2bfloat16(f);
  return *reinterpret_cast<ushort*>(&t);
}

// ---------------- zero vt tail slots (tokens 784..831 equivalents) -----------
// NTOK = 12*64+16: the last 64-slot phi tile of each (ch,b) row only gets 16
// valid slots written by the QKV epilogue. The rest MUST be zero: they pair
// with P==0 in the last PV k-tile, and 0*NaN-garbage = NaN (the r6-r8 bug:
// vt overlaps dead f32 lx_cm, whose low halfwords are NaN-pattern bf16s).
__global__ __launch_bounds__(256) void zero_vt_tail(__hip_bfloat16* __restrict__ vt) {
  const bf16x8 z8 = {0, 0, 0, 0, 0, 0, 0, 0};
  int i = blockIdx.x * 256 + threadIdx.x;   // CH*BATCH*8 chunks of 8 bf16
  if (i < CH * BATCH * 8) {
    int chunk = i & 7, cb = i >> 3;
    int ch = cb >> 4, b = cb & 15;
    *(bf16x8*)(vt + (size_t)ch * VT_CSTRIDE + b * VT_BSTRIDE + 768 + chunk * 8) = z8;
  }
}

// ---------------- merged weight/bias convert ---------------------------------
__global__ __launch_bounds__(256) void cvt_all(
    const float* __restrict__ q_w, const float* __restrict__ k_w,
    const float* __restrict__ v_w, const float* __restrict__ proj_w,
    const float* __restrict__ ffn1_w, const float* __restrict__ ffn2_w,
    const float* __restrict__ g, const float* __restrict__ vv,
    const float* __restrict__ qb, const float* __restrict__ kb,
    const float* __restrict__ vb,
    __hip_bfloat16* __restrict__ wdst, float* __restrict__ qkvb) {
  int i = blockIdx.x * 256 + threadIdx.x;
  if (i < QKVC) {
    float bvv;
    if (i < CH) bvv = qb[i] * LAMBDA;
    else if (i < 2 * CH) bvv = kb[i - CH];
    else bvv = vb[i - 2 * CH];
    qkvb[i] = bvv;
  }
  if (i < NW_ALL) {
    float val;
    if (i < WCC) val = q_w[i] * LAMBDA;
    else if (i < 2 * WCC) val = k_w[i - WCC];
    else if (i < 3 * WCC) val = v_w[i - 2 * WCC];
    else if (i < 4 * WCC) val = proj_w[i - 3 * WCC];
    else if (i < 4 * WCC + C4 * CH) {
      int j = i - 4 * WCC;
      int c = j % CH;
      val = ffn1_w[j] * g[c] * rsqrtf(vv[c] + BN_EPS);
    } else {
      val = ffn2_w[i - 4 * WCC - C4 * CH];
    }
    wdst[i] = __float2bfloat16(val);
  }
}

// ---------------- parallel BN2-bias fold into ffn1 bias ----------------------
__global__ __launch_bounds__(256) void prep_bias2(
    const float* __restrict__ ffn1_w, const float* __restrict__ ffn1_b,
    const float* __restrict__ g, const float* __restrict__ bb,
    const float* __restrict__ m, const float* __restrict__ v,
    float* __restrict__ fbias) {
  int w = threadIdx.x >> 6, lane = threadIdx.x & 63;
  int o = blockIdx.x * 4 + w;  // 384 blocks x 4 waves = 1536 outputs
  float acc = 0.f;
  for (int c = lane; c < CH; c += 64) {
    float s = g[c] * rsqrtf(v[c] + BN_EPS);
    acc += ffn1_w[(size_t)o * CH + c] * (bb[c] - m[c] * s);
  }
#pragma unroll
  for (int off = 32; off; off >>= 1) acc += __shfl_xor(acc, off, 64);
  if (lane == 0) fbias[o] = ffn1_b[o] + acc;
}

// ---------------- depthwise 3x3 conv + bias + BN1 (folded), channel-major ----
__global__ __launch_bounds__(256) void dwconv_bn(
    const float* __restrict__ x, const float* __restrict__ w,
    const float* __restrict__ cb, const float* __restrict__ g,
    const float* __restrict__ bnb, const float* __restrict__ m,
    const float* __restrict__ var, float* __restrict__ lx) {
  int bc = blockIdx.x;
  int c = bc % CH;
  const float* xp = x + (size_t)bc * NTOK;
  float* op = lx + (size_t)bc * NTOK;
  float k[9];
#pragma unroll
  for (int i = 0; i < 9; ++i) k[i] = w[c * 9 + i];
  float s = g[c] * rsqrtf(var[c] + BN_EPS);
  float sh = (cb[c] - m[c]) * s + bnb[c];
  for (int n = threadIdx.x; n < NTOK; n += 256) {
    int y = n / WW, xx = n - y * WW;
    float acc = 0.f;
#pragma unroll
    for (int ky = -1; ky <= 1; ++ky) {
      int yy = y + ky;
      if (yy < 0 || yy >= HH) continue;
#pragma unroll
      for (int kx = -1; kx <= 1; ++kx) {
        int x2 = xx + kx;
        if (x2 < 0 || x2 >= WW) continue;
        acc += k[(ky + 1) * 3 + (kx + 1)] * xp[yy * WW + x2];
      }
    }
    op[n] = acc * s + sh;
  }
}

// ---------------- transpose+convert: [B][C][N] f32 -> [B*N][C] bf16 ----------
__global__ __launch_bounds__(256) void transpose_cvt(
    const float* __restrict__ in, __hip_bfloat16* __restrict__ outb) {
  __shared__ float t[32][33];
  int b = blockIdx.z, c0 = blockIdx.y * 32, n0 = blockIdx.x * 32;
  int tx = threadIdx.x & 31, ty = threadIdx.x >> 5;
  for (int cc = ty; cc < 32; cc += 8) {
    int n = n0 + tx;
    t[cc][tx] = (n < NTOK) ? in[((size_t)b * CH + c0 + cc) * NTOK + n] : 0.f;
  }
  __syncthreads();
  for (int nn = ty; nn < 32; nn += 8) {
    int n = n0 + nn;
    if (n < NTOK) outb[((size_t)b * NTOK + n) * CH + c0 + tx] = __float2bfloat16(t[tx][nn]);
  }
}

// ---------------- MFMA GEMM --------------------------------------------------
// EPI 0: QKV split epilogue — cols 0..767 -> qk_act [tok][768]; cols 768..1151
//        -> vt [ch][b][13*64 phi-permuted] (phi = 4*(t&15) | (t>>4) within 64)
// EPI 1: out bf16 [m][NB], += bias[n] + resid[m*NB+n]
// EPI 2: out bf16 [m][NB], += bias[n], exact GELU
// EPI 3: m=outch(384), n=token; out f32 [b][384][784], += bias[m] + resid[n*384+m]
template <int EPI>
__global__ __launch_bounds__(256) void gemm_mfma(
    const __hip_bfloat16* __restrict__ Arows, const __hip_bfloat16* __restrict__ Brows,
    const float* __restrict__ bias, const __hip_bfloat16* __restrict__ resid,
    void* __restrict__ outp, void* __restrict__ outp2, int K) {
  __shared__ __align__(16) ushort As[128 * 32];
  __shared__ __align__(16) ushort Bs[128 * 32];
  const int tid = threadIdx.x;
  const int w = tid >> 6;
  const int lane = tid & 63;
  const int quad = lane >> 4;
  const int l16 = lane & 15;
  const int m0 = blockIdx.y * 128;
  const int n0 = blockIdx.x * 128;
  const int wm = (w & 1) * 64, wn = (w >> 1) * 64;
  const int NB = gridDim.x * 128;
  const int MB = gridDim.y * 128;

  f32x4 zero = {0.f, 0.f, 0.f, 0.f};
  f32x4 acc[4][4];
#pragma unroll
  for (int i = 0; i < 4; ++i)
#pragma unroll
    for (int j = 0; j < 4; ++j) acc[i][j] = zero;

  for (int k0 = 0; k0 < K; k0 += 32) {
    __syncthreads();
#pragma unroll
    for (int t = 0; t < 2; ++t) {
      int c = w * 128 + t * 64 + lane;
      int row = c >> 2;
      int sg = (c & 3) ^ ((c >> 3) & 3);
      async16(As + (size_t)(w * 128 + t * 64) * 8,
              Arows + (size_t)(m0 + row) * K + k0 + sg * 8);
    }
#pragma unroll
    for (int t = 0; t < 2; ++t) {
      int c = w * 128 + t * 64 + lane;
      int row = c >> 2;
      int sg = (c & 3) ^ ((c >> 3) & 3);
      async16(Bs + (size_t)(w * 128 + t * 64) * 8,
              Brows + (size_t)(n0 + row) * K + k0 + sg * 8);
    }
    __syncthreads();

    bf16x8 af[4], bf[4];
#pragma unroll
    for (int i = 0; i < 4; ++i) {
      int ra = wm + i * 16 + l16;
      int sa = quad ^ ((ra >> 1) & 3);
      af[i] = *(const bf16x8*)&As[ra * 32 + sa * 8];
      int rb = wn + i * 16 + l16;
      int sb = quad ^ ((rb >> 1) & 3);
      bf[i] = *(const bf16x8*)&Bs[rb * 32 + sb * 8];
    }
#pragma unroll
    for (int i = 0; i < 4; ++i)
#pragma unroll
      for (int j = 0; j < 4; ++j)
        acc[i][j] = __builtin_amdgcn_mfma_f32_16x16x32_bf16(af[i], bf[j], acc[i][j], 0, 0, 0);
  }

#pragma unroll
  for (int i = 0; i < 4; ++i) {
#pragma unroll
    for (int j = 0; j < 4; ++j) {
#pragma unroll
      for (int r = 0; r < 4; ++r) {
        int mrow = m0 + wm + i * 16 + quad * 4 + r;
        int ncol = n0 + wn + j * 16 + l16;
        float val = acc[i][j][r];
        if (EPI == 0) {
          val += bias[ncol];
          if (ncol < 2 * CH) {
            ((__hip_bfloat16*)outp)[(size_t)mrow * (2 * CH) + ncol] = __float2bfloat16(val);
          } else {
            int ch = ncol - 2 * CH;
            int bq = mrow / NTOK;
            int tb = mrow - bq * NTOK;
            int tt = tb & 63, t64 = tb >> 6;
            int phi = ((tt & 15) << 2) | (tt >> 4);
            ((__hip_bfloat16*)outp2)[(size_t)ch * VT_CSTRIDE + bq * VT_BSTRIDE + t64 * 64 + phi] =
                __float2bfloat16(val);
          }
        } else if (EPI <= 2) {
          val += bias[ncol];
          if (EPI == 1) val += bf2f(resid[(size_t)mrow * NB + ncol]);
          if (EPI == 2) val = 0.5f * val * (1.f + erff(val * 0.70710678118654752f));
          ((__hip_bfloat16*)outp)[(size_t)mrow * NB + ncol] = __float2bfloat16(val);
        } else {
          val += bias[mrow];
          val += bf2f(resid[(size_t)ncol * MB + mrow]);
          int bq = ncol / NTOK, nn = ncol - bq * NTOK;
          ((float*)outp)[((size_t)bq * MB + mrow) * NTOK + nn] = val;
        }
      }
    }
  }
}

// ---------------- MFMA flash attention v2c -----------------------------------
// Block = 4 waves x 32 queries = 128-query tile of one (b,h).
// Q fragments in registers (prescaled by LAMBDA at QKV-gen -> exp2 softmax).
// K from qk_act (token-major); V from vt (channel-major, phi-permuted per
// 64-token tile; tail slots pre-zeroed by zero_vt_tail). phi applied to BOTH
// P and V key axes -> PV invariant. P tile: ushort LDS + scalar ushort stores
// + bf16x8 loads (r5 HW-proven pattern) with a barrier before the PV reads.
__global__ __launch_bounds__(256) void attention_mfma2(
    const __hip_bfloat16* __restrict__ qk, const __hip_bfloat16* __restrict__ vt,
    __hip_bfloat16* __restrict__ ob) {
  __shared__ __align__(16) ushort Ks[KTL][72];   // 72-stride rows, 2-way-free
  __shared__ __align__(16) ushort Vts[HDIM][72];
  __shared__ __align__(16) ushort Ps[4][32][72]; // per-wave P strips

  const int tid = threadIdx.x;
  const int w = tid >> 6, lane = tid & 63;
  const int quad = lane >> 4, l16 = lane & 15;
  const int h = blockIdx.y, b = blockIdx.z;
  const int n0 = blockIdx.x * QTL;
  const size_t tokbase = (size_t)b * NTOK;
  const bf16x8 z8 = {0, 0, 0, 0, 0, 0, 0, 0};

  // Q fragments: 2 strips x 2 k-halves; explicitly zero dims 48..63.
  bf16x8 aq[2][2];
#pragma unroll
  for (int s = 0; s < 2; ++s) {
    int tok = n0 + w * 32 + s * 16 + l16;
    if (tok >= NTOK) tok = NTOK - 1;  // clamp; masked rows never stored
#pragma unroll
    for (int kk = 0; kk < 2; ++kk)
      aq[s][kk] = *(const bf16x8*)(qk + (tokbase + tok) * (2 * CH) + h * HDIM + kk * 32 + quad * 8);
    if (quad >= 2) aq[s][1] = z8;  // dims 48..63 -> zero
  }

  bf16x8 kreg[2], vreg[2];
  auto loadK = [&](int m0k) {
#pragma unroll
    for (int t = 0; t < 2; ++t) {
      int c = tid + t * 256;
      int row = c >> 3, hc = c & 7;
      int tok = m0k + row;
      bf16x8 val = z8;
      if (hc < 6 && tok < NTOK)
        val = *(const bf16x8*)(qk + (tokbase + tok) * (2 * CH) + CH + h * HDIM + hc * 8);
      kreg[t] = val;
    }
  };
  auto loadV = [&](int m0k) {
#pragma unroll
    for (int t = 0; t < 2; ++t) {
      int c = tid + t * 256;
      if (c < HDIM * 8) {
        int d = c >> 3, hc = c & 7;
        vreg[t] = *(const bf16x8*)(vt + (size_t)(h * HDIM + d) * VT_CSTRIDE + b * VT_BSTRIDE + m0k + hc * 8);
      }
    }
  };

  float m_i[2][4], l_i[2][4];
#pragma unroll
  for (int s = 0; s < 2; ++s)
#pragma unroll
    for (int r = 0; r < 4; ++r) { m_i[s][r] = -1e30f; l_i[s][r] = 0.f; }
  f32x4 o[2][3];
  const f32x4 zf = {0.f, 0.f, 0.f, 0.f};
#pragma unroll
  for (int s = 0; s < 2; ++s)
#pragma unroll
    for (int t = 0; t < 3; ++t) o[s][t] = zf;

  loadK(0);
  loadV(0);

  for (int m0 = 0; m0 < NTOK; m0 += KTL) {
    __syncthreads();  // all waves done reading Ks/Vts (and Ps) of previous tile
#pragma unroll
    for (int t = 0; t < 2; ++t) {
      int c = tid + t * 256;
      *(bf16x8*)&Ks[c >> 3][(c & 7) * 8] = kreg[t];
    }
#pragma unroll
    for (int t = 0; t < 2; ++t) {
      int c = tid + t * 256;
      if (c < HDIM * 8) *(bf16x8*)&Vts[c >> 3][(c & 7) * 8] = vreg[t];
    }
    __syncthreads();  // tile staged
    int mn = m0 + KTL;
    if (mn < NTOK) { loadK(mn); loadV(mn); }  // prefetch overlaps compute

    // S: 2 strips x 64 keys, K=64
    f32x4 sa[2][4];
#pragma unroll
    for (int s = 0; s < 2; ++s)
#pragma unroll
      for (int j = 0; j < 4; ++j) sa[s][j] = zf;
#pragma unroll
    for (int kk = 0; kk < 2; ++kk) {
#pragma unroll
      for (int j = 0; j < 4; ++j) {
        bf16x8 kf = *(const bf16x8*)&Ks[j * 16 + l16][kk * 32 + quad * 8];
        sa[0][j] = __builtin_amdgcn_mfma_f32_16x16x32_bf16(aq[0][kk], kf, sa[0][j], 0, 0, 0);
        sa[1][j] = __builtin_amdgcn_mfma_f32_16x16x32_bf16(aq[1][kk], kf, sa[1][j], 0, 0, 0);
      }
    }

    // online softmax (log2 domain; LAMBDA pre-folded into Q).
    // P stored in phi-order: key tt = j*16+l16 -> column 4*l16+j.
    const bool lastT = (m0 + KTL > NTOK);
    float alpha[2][4];
#pragma unroll
    for (int s = 0; s < 2; ++s) {
#pragma unroll
      for (int r = 0; r < 4; ++r) {
        float sv0 = sa[s][0][r], sv1 = sa[s][1][r], sv2 = sa[s][2][r], sv3 = sa[s][3][r];
        if (lastT) {
          if (m0 + 0 * 16 + l16 >= NTOK) sv0 = -1e30f;
          if (m0 + 1 * 16 + l16 >= NTOK) sv1 = -1e30f;
          if (m0 + 2 * 16 + l16 >= NTOK) sv2 = -1e30f;
          if (m0 + 3 * 16 + l16 >= NTOK) sv3 = -1e30f;
        }
        float mx = fmaxf(fmaxf(sv0, sv1), fmaxf(sv2, sv3));
#pragma unroll
        for (int off = 1; off < 16; off <<= 1) mx = fmaxf(mx, __shfl_xor(mx, off, 16));
        float mnew = fmaxf(m_i[s][r], mx);
        float al = __builtin_amdgcn_exp2f(m_i[s][r] - mnew);
        alpha[s][r] = al;
        m_i[s][r] = mnew;
        float p0 = __builtin_amdgcn_exp2f(sv0 - mnew);
        float p1 = __builtin_amdgcn_exp2f(sv1 - mnew);
        float p2 = __builtin_amdgcn_exp2f(sv2 - mnew);
        float p3 = __builtin_amdgcn_exp2f(sv3 - mnew);
        float sum = (p0 + p1) + (p2 + p3);
        int prow = s * 16 + quad * 4 + r;
        Ps[w][prow][4 * l16 + 0] = f2bf_bits(p0);
        Ps[w][prow][4 * l16 + 1] = f2bf_bits(p1);
        Ps[w][prow][4 * l16 + 2] = f2bf_bits(p2);
        Ps[w][prow][4 * l16 + 3] = f2bf_bits(p3);
#pragma unroll
        for (int off = 1; off < 16; off <<= 1) sum += __shfl_xor(sum, off, 16);
        l_i[s][r] = l_i[s][r] * al + sum;
      }
    }
#pragma unroll
    for (int s = 0; s < 2; ++s)
#pragma unroll
      for (int t = 0; t < 3; ++t)
#pragma unroll
        for (int r = 0; r < 4; ++r) o[s][t][r] *= alpha[s][r];

    __syncthreads();  // LDS fence: all P writes retired before any P read

    // PV: P (phi-order) x V (phi-order)
    bf16x8 pf[2][2];
#pragma unroll
    for (int s = 0; s < 2; ++s)
#pragma unroll
      for (int kk = 0; kk < 2; ++kk)
        pf[s][kk] = *(const bf16x8*)&Ps[w][s * 16 + l16][kk * 32 + quad * 8];
#pragma unroll
    for (int kk = 0; kk < 2; ++kk) {
#pragma unroll
      for (int t = 0; t < 3; ++t) {
        bf16x8 vf = *(const bf16x8*)&Vts[t * 16 + l16][kk * 32 + quad * 8];
        o[0][t] = __builtin_amdgcn_mfma_f32_16x16x32_bf16(pf[0][kk], vf, o[0][t], 0, 0, 0);
        o[1][t] = __builtin_amdgcn_mfma_f32_16x16x32_bf16(pf[1][kk], vf, o[1][t], 0, 0, 0);
      }
    }
  }

  // epilogue
#pragma unroll
  for (int s = 0; s < 2; ++s) {
    float inv[4];
#pragma unroll
    for (int r = 0; r < 4; ++r) inv[r] = __builtin_amdgcn_rcpf(l_i[s][r]);
#pragma unroll
    for (int t = 0; t < 3; ++t) {
#pragma unroll
      for (int r = 0; r < 4; ++r) {
        int tok = n0 + w * 32 + s * 16 + quad * 4 + r;
        if (tok < NTOK)
          ob[(tokbase + tok) * CH + h * HDIM + t * 16 + l16] =
              __float2bfloat16(o[s][t][r] * inv[r]);
      }
    }
  }
}

// ---------------- launch -----------------------------------------------------
extern "C" void kernel_launch(void* const* d_in, const int* in_sizes, int n_in,
                              void* d_out, int out_size, void* d_ws, size_t ws_size,
                              hipStream_t stream) {
  const float* x       = (const float*)d_in[0];
  const float* local_w = (const float*)d_in[1];
  const float* local_b = (const float*)d_in[2];
  const float* bn1_g   = (const float*)d_in[3];
  const float* bn1_b   = (const float*)d_in[4];
  const float* bn1_m   = (const float*)d_in[5];
  const float* bn1_v   = (const float*)d_in[6];
  const float* q_w     = (const float*)d_in[7];
  const float* q_b     = (const float*)d_in[8];
  const float* k_w     = (const float*)d_in[9];
  const float* k_b     = (const float*)d_in[10];
  const float* v_w     = (const float*)d_in[11];
  const float* v_b     = (const float*)d_in[12];
  const float* proj_w  = (const float*)d_in[13];
  const float* proj_b  = (const float*)d_in[14];
  const float* ffn1_w  = (const float*)d_in[15];
  const float* ffn1_b  = (const float*)d_in[16];
  const float* ffn2_w  = (const float*)d_in[17];
  const float* ffn2_b  = (const float*)d_in[18];
  const float* bn2_g   = (const float*)d_in[19];
  const float* bn2_b   = (const float*)d_in[20];
  const float* bn2_m   = (const float*)d_in[21];
  const float* bn2_v   = (const float*)d_in[22];

  char* wsb = (char*)d_ws;
  // region [0, 38.5MB): lx_cm (f32, dead after transpose) -> vt (written by
  // zero_vt_tail+gemm0, dead after attention) & qk_act -> gelu_a clobbers both.
  float*          lx_cm   = (float*)(wsb + 0);
  __hip_bfloat16* vt      = (__hip_bfloat16*)(wsb + 0);          // 10.2 MB
  __hip_bfloat16* qk_act  = (__hip_bfloat16*)(wsb + 19267584);   // 19.3 MB
  __hip_bfloat16* gelu_a  = (__hip_bfloat16*)(wsb + 0);          // 38.5 MB
  __hip_bfloat16* attn_a  = (__hip_bfloat16*)(wsb + 48168960);
  __hip_bfloat16* lx_tm   = (__hip_bfloat16*)(wsb + 57802752);
  __hip_bfloat16* resid_a = (__hip_bfloat16*)(wsb + 67436544);
  __hip_bfloat16* w_qkv   = (__hip_bfloat16*)(wsb + 77070336);   // contiguous:
  __hip_bfloat16* w_proj  = (__hip_bfloat16*)(wsb + 77955072);   //  qkv|proj|
  __hip_bfloat16* w_ffn1  = (__hip_bfloat16*)(wsb + 78249984);   //  ffn1|ffn2
  __hip_bfloat16* w_ffn2  = (__hip_bfloat16*)(wsb + 79429632);
  float*          b_qkv   = (float*)(wsb + 80609280);
  float*          b_ffn1  = (float*)(wsb + 80613888);

  cvt_all<<<dim3((NW_ALL + 255) / 256), dim3(256), 0, stream>>>(
      q_w, k_w, v_w, proj_w, ffn1_w, ffn2_w, bn2_g, bn2_v, q_b, k_b, v_b,
      w_qkv, b_qkv);
  prep_bias2<<<dim3(C4 / 4), dim3(256), 0, stream>>>(
      ffn1_w, ffn1_b, bn2_g, bn2_b, bn2_m, bn2_v, b_ffn1);

  dwconv_bn<<<dim3(BATCH * CH), dim3(256), 0, stream>>>(
      x, local_w, local_b, bn1_g, bn1_b, bn1_m, bn1_v, lx_cm);
  transpose_cvt<<<dim3(25, 12, BATCH), dim3(256), 0, stream>>>(lx_cm, lx_tm);

  // lx_cm now dead: zero the vt tail BEFORE gemm0 writes the valid slots
  zero_vt_tail<<<dim3((CH * BATCH * 8 + 255) / 256), dim3(256), 0, stream>>>(vt);

  // fused QKV GEMM -> qk_act [tok][768] + vt (phi-permuted V^T)
  gemm_mfma<0><<<dim3(QKVC / 128, NTOT / 128), dim3(256), 0, stream>>>(
      lx_tm, w_qkv, b_qkv, nullptr, qk_act, vt, CH);

  attention_mfma2<<<dim3((NTOK + QTL - 1) / QTL, NHEADS, BATCH), dim3(256), 0, stream>>>(
      qk_act, vt, attn_a);

  gemm_mfma<1><<<dim3(CH / 128, NTOT / 128), dim3(256), 0, stream>>>(
      attn_a, w_proj, proj_b, lx_tm, resid_a, nullptr, CH);

  gemm_mfma<2><<<dim3(C4 / 128, NTOT / 128), dim3(256), 0, stream>>>(
      resid_a, w_ffn1, b_ffn1, nullptr, gelu_a, nullptr, CH);

  gemm_mfma<3><<<dim3(NTOT / 128, CH / 128), dim3(256), 0, stream>>>(
      w_ffn2, gelu_a, ffn2_b, resid_a, d_out, nullptr, C4);
}

// Round 10
// 365.813 us; speedup vs baseline: 7.2747x; 1.0331x over previous
//
#include <hip/hip_runtime.h>
#include <hip/hip_bf16.h>
#include <math.h>

#define BATCH 16
#define CH 384
#define HH 28
#define WW 28
#define NTOK 784
#define NTOT (BATCH * NTOK)   // 12544 tokens, 98 tiles of 128
#define NHEADS 8
#define HDIM 48
#define C4 1536
#define QKVC 1152
#define BN_EPS 1e-5f
#define QTL 128               // queries per attention block
#define KTL 64                // keys per attention k-tile
#define WCC (CH * CH)         // 147456
#define NW_ALL (4 * WCC + 2 * C4 * CH)
// 1/sqrt(48) * log2(e): folded into Q weights/bias so softmax uses exp2 directly
#define LAMBDA (0.14433756729740643f * 1.4426950408889634f)
// vt layout: [384 v-channels][16 batches][832 = 13*64 phi-permuted tokens]
#define VT_BSTRIDE 832
#define VT_CSTRIDE (16 * 832)

typedef __attribute__((ext_vector_type(8))) short bf16x8;
typedef __attribute__((ext_vector_type(4))) float f32x4;

__device__ __forceinline__ void async16(void* lds, const void* g) {
  __builtin_amdgcn_global_load_lds(
      (const __attribute__((address_space(1))) void*)g,
      (__attribute__((address_space(3))) void*)lds, 16, 0, 0);
}
__device__ __forceinline__ float bf2f(__hip_bfloat16 v) { return __bfloat162float(v); }
__device__ __forceinline__ ushort f2bf_bits(float f) {
  __hip_bfloat16 t = __float2bfloat16(f);
  return *reinterpret_cast<ushort*>(&t);
}

// ---------------- merged prep: weight cvt + qkv bias + ffn1-bias fold + vt tail
__global__ __launch_bounds__(256) void cvt_all(
    const float* __restrict__ q_w, const float* __restrict__ k_w,
    const float* __restrict__ v_w, const float* __restrict__ proj_w,
    const float* __restrict__ ffn1_w, const float* __restrict__ ffn2_w,
    const float* __restrict__ g, const float* __restrict__ vv,
    const float* __restrict__ qb, const float* __restrict__ kb,
    const float* __restrict__ vb, const float* __restrict__ fb1,
    const float* __restrict__ bb2, const float* __restrict__ mm2,
    __hip_bfloat16* __restrict__ wdst, float* __restrict__ qkvb,
    float* __restrict__ fbias, __hip_bfloat16* __restrict__ vtp) {
  int i = blockIdx.x * 256 + threadIdx.x;
  if (i < QKVC) {
    float bvv;
    if (i < CH) bvv = qb[i] * LAMBDA;
    else if (i < 2 * CH) bvv = kb[i - CH];
    else bvv = vb[i - 2 * CH];
    qkvb[i] = bvv;
  }
  // zero vt tail slots (NTOK=12*64+16: last 64-slot phi tile gets only 16
  // valid writes from the QKV epilogue; rest pairs with P==0 and must be 0,
  // since 0*NaN-garbage = NaN — the r6-r8 all-NaN bug)
  if (i < CH * BATCH * 8) {
    const bf16x8 z8 = {0, 0, 0, 0, 0, 0, 0, 0};
    int chunk = i & 7, cb = i >> 3;
    int ch = cb >> 4, b = cb & 15;
    *(bf16x8*)(vtp + (size_t)ch * VT_CSTRIDE + b * VT_BSTRIDE + 768 + chunk * 8) = z8;
  }
  if (i < NW_ALL) {
    float val;
    if (i < WCC) val = q_w[i] * LAMBDA;
    else if (i < 2 * WCC) val = k_w[i - WCC];
    else if (i < 3 * WCC) val = v_w[i - 2 * WCC];
    else if (i < 4 * WCC) val = proj_w[i - 3 * WCC];
    else if (i < 4 * WCC + C4 * CH) {
      int j = i - 4 * WCC;
      int c = j % CH;
      val = ffn1_w[j] * g[c] * rsqrtf(vv[c] + BN_EPS);
    } else {
      val = ffn2_w[i - 4 * WCC - C4 * CH];
    }
    wdst[i] = __float2bfloat16(val);
  }
  // BN2-shift fold into ffn1 bias: blocks 0..383, one output per wave
  if (blockIdx.x < C4 / 4) {
    int w = threadIdx.x >> 6, lane = threadIdx.x & 63;
    int o = blockIdx.x * 4 + w;
    float acc = 0.f;
    for (int c = lane; c < CH; c += 64) {
      float s = g[c] * rsqrtf(vv[c] + BN_EPS);
      acc += ffn1_w[(size_t)o * CH + c] * (bb2[c] - mm2[c] * s);
    }
#pragma unroll
    for (int off = 32; off; off >>= 1) acc += __shfl_xor(acc, off, 64);
    if (lane == 0) fbias[o] = fb1[o] + acc;
  }
}

// ---------------- depthwise 3x3 conv + bias + BN1 (folded) -> bf16 ch-major --
__global__ __launch_bounds__(256) void dwconv_bn(
    const float* __restrict__ x, const float* __restrict__ w,
    const float* __restrict__ cb, const float* __restrict__ g,
    const float* __restrict__ bnb, const float* __restrict__ m,
    const float* __restrict__ var, __hip_bfloat16* __restrict__ lx) {
  int bc = blockIdx.x;
  int c = bc % CH;
  const float* xp = x + (size_t)bc * NTOK;
  __hip_bfloat16* op = lx + (size_t)bc * NTOK;
  float k[9];
#pragma unroll
  for (int i = 0; i < 9; ++i) k[i] = w[c * 9 + i];
  float s = g[c] * rsqrtf(var[c] + BN_EPS);
  float sh = (cb[c] - m[c]) * s + bnb[c];
  for (int n = threadIdx.x; n < NTOK; n += 256) {
    int y = n / WW, xx = n - y * WW;
    float acc = 0.f;
#pragma unroll
    for (int ky = -1; ky <= 1; ++ky) {
      int yy = y + ky;
      if (yy < 0 || yy >= HH) continue;
#pragma unroll
      for (int kx = -1; kx <= 1; ++kx) {
        int x2 = xx + kx;
        if (x2 < 0 || x2 >= WW) continue;
        acc += k[(ky + 1) * 3 + (kx + 1)] * xp[yy * WW + x2];
      }
    }
    op[n] = __float2bfloat16(acc * s + sh);
  }
}

// ---------------- transpose: [B][C][N] bf16 -> [B*N][C] bf16 (bit-mover) -----
__global__ __launch_bounds__(256) void transpose_b(
    const ushort* __restrict__ in, ushort* __restrict__ outb) {
  __shared__ ushort t[32][34];
  int b = blockIdx.z, c0 = blockIdx.y * 32, n0 = blockIdx.x * 32;
  int tx = threadIdx.x & 31, ty = threadIdx.x >> 5;
  for (int cc = ty; cc < 32; cc += 8) {
    int n = n0 + tx;
    t[cc][tx] = (n < NTOK) ? in[((size_t)b * CH + c0 + cc) * NTOK + n] : (ushort)0;
  }
  __syncthreads();
  for (int nn = ty; nn < 32; nn += 8) {
    int n = n0 + nn;
    if (n < NTOK) outb[((size_t)b * NTOK + n) * CH + c0 + tx] = t[tx][nn];
  }
}

// ---------------- MFMA GEMM, tileable TM x TN --------------------------------
// EPI 0: QKV split epilogue — cols 0..767 -> qk_act [tok][768]; cols 768..1151
//        -> vt [ch][b][13*64 phi-permuted] (phi = 4*(t&15) | (t>>4) within 64)
// EPI 1: out bf16 [m][NB], += bias[n] + resid[m*NB+n]
// EPI 2: out bf16 [m][NB], += bias[n], exact GELU
// EPI 3: m=outch(384), n=token; out f32 [b][384][784], += bias[m] + resid[n*384+m]
template <int EPI, int TM, int TN>
__global__ __launch_bounds__(256) void gemm_mfma(
    const __hip_bfloat16* __restrict__ Arows, const __hip_bfloat16* __restrict__ Brows,
    const float* __restrict__ bias, const __hip_bfloat16* __restrict__ resid,
    void* __restrict__ outp, void* __restrict__ outp2, int K) {
  constexpr int NI = TM / 32, NJ = TN / 32;
  __shared__ __align__(16) ushort As[TM * 32];
  __shared__ __align__(16) ushort Bs[TN * 32];
  const int tid = threadIdx.x;
  const int w = tid >> 6;
  const int lane = tid & 63;
  const int quad = lane >> 4;
  const int l16 = lane & 15;
  const int m0 = blockIdx.y * TM;
  const int n0 = blockIdx.x * TN;
  const int wm = (w & 1) * (TM / 2), wn = (w >> 1) * (TN / 2);
  const int NB = gridDim.x * TN;
  const int MB = gridDim.y * TM;

  f32x4 zero = {0.f, 0.f, 0.f, 0.f};
  f32x4 acc[NI][NJ];
#pragma unroll
  for (int i = 0; i < NI; ++i)
#pragma unroll
    for (int j = 0; j < NJ; ++j) acc[i][j] = zero;

  for (int k0 = 0; k0 < K; k0 += 32) {
    __syncthreads();
#pragma unroll
    for (int it = 0; it < (TM * 4 + 255) / 256; ++it) {
      int cbase = it * 256 + w * 64;
      int c = cbase + lane;
      int row = c >> 2;
      int sg = (c & 3) ^ ((c >> 3) & 3);
      async16(As + (size_t)cbase * 8,
              Arows + (size_t)(m0 + row) * K + k0 + sg * 8);
    }
#pragma unroll
    for (int it = 0; it < (TN * 4 + 255) / 256; ++it) {
      int cbase = it * 256 + w * 64;
      int c = cbase + lane;
      int row = c >> 2;
      int sg = (c & 3) ^ ((c >> 3) & 3);
      async16(Bs + (size_t)cbase * 8,
              Brows + (size_t)(n0 + row) * K + k0 + sg * 8);
    }
    __syncthreads();

    bf16x8 af[NI], bf[NJ];
#pragma unroll
    for (int i = 0; i < NI; ++i) {
      int ra = wm + i * 16 + l16;
      int sa = quad ^ ((ra >> 1) & 3);
      af[i] = *(const bf16x8*)&As[ra * 32 + sa * 8];
    }
#pragma unroll
    for (int j = 0; j < NJ; ++j) {
      int rb = wn + j * 16 + l16;
      int sb = quad ^ ((rb >> 1) & 3);
      bf[j] = *(const bf16x8*)&Bs[rb * 32 + sb * 8];
    }
#pragma unroll
    for (int i = 0; i < NI; ++i)
#pragma unroll
      for (int j = 0; j < NJ; ++j)
        acc[i][j] = __builtin_amdgcn_mfma_f32_16x16x32_bf16(af[i], bf[j], acc[i][j], 0, 0, 0);
  }

#pragma unroll
  for (int i = 0; i < NI; ++i) {
#pragma unroll
    for (int j = 0; j < NJ; ++j) {
#pragma unroll
      for (int r = 0; r < 4; ++r) {
        int mrow = m0 + wm + i * 16 + quad * 4 + r;
        int ncol = n0 + wn + j * 16 + l16;
        float val = acc[i][j][r];
        if (EPI == 0) {
          val += bias[ncol];
          if (ncol < 2 * CH) {
            ((__hip_bfloat16*)outp)[(size_t)mrow * (2 * CH) + ncol] = __float2bfloat16(val);
          } else {
            int ch = ncol - 2 * CH;
            int bq = mrow / NTOK;
            int tb = mrow - bq * NTOK;
            int tt = tb & 63, t64 = tb >> 6;
            int phi = ((tt & 15) << 2) | (tt >> 4);
            ((__hip_bfloat16*)outp2)[(size_t)ch * VT_CSTRIDE + bq * VT_BSTRIDE + t64 * 64 + phi] =
                __float2bfloat16(val);
          }
        } else if (EPI <= 2) {
          val += bias[ncol];
          if (EPI == 1) val += bf2f(resid[(size_t)mrow * NB + ncol]);
          if (EPI == 2) val = 0.5f * val * (1.f + erff(val * 0.70710678118654752f));
          ((__hip_bfloat16*)outp)[(size_t)mrow * NB + ncol] = __float2bfloat16(val);
        } else {
          val += bias[mrow];
          val += bf2f(resid[(size_t)ncol * MB + mrow]);
          int bq = ncol / NTOK, nn = ncol - bq * NTOK;
          ((float*)outp)[((size_t)bq * MB + mrow) * NTOK + nn] = val;
        }
      }
    }
  }
}

// ---------------- MFMA flash attention (unchanged from r9, HW-proven) --------
__global__ __launch_bounds__(256) void attention_mfma2(
    const __hip_bfloat16* __restrict__ qk, const __hip_bfloat16* __restrict__ vt,
    __hip_bfloat16* __restrict__ ob) {
  __shared__ __align__(16) ushort Ks[KTL][72];   // 72-stride rows, 2-way-free
  __shared__ __align__(16) ushort Vts[HDIM][72];
  __shared__ __align__(16) ushort Ps[4][32][72]; // per-wave P strips

  const int tid = threadIdx.x;
  const int w = tid >> 6, lane = tid & 63;
  const int quad = lane >> 4, l16 = lane & 15;
  const int h = blockIdx.y, b = blockIdx.z;
  const int n0 = blockIdx.x * QTL;
  const size_t tokbase = (size_t)b * NTOK;
  const bf16x8 z8 = {0, 0, 0, 0, 0, 0, 0, 0};

  bf16x8 aq[2][2];
#pragma unroll
  for (int s = 0; s < 2; ++s) {
    int tok = n0 + w * 32 + s * 16 + l16;
    if (tok >= NTOK) tok = NTOK - 1;  // clamp; masked rows never stored
#pragma unroll
    for (int kk = 0; kk < 2; ++kk)
      aq[s][kk] = *(const bf16x8*)(qk + (tokbase + tok) * (2 * CH) + h * HDIM + kk * 32 + quad * 8);
    if (quad >= 2) aq[s][1] = z8;  // dims 48..63 -> zero
  }

  bf16x8 kreg[2], vreg[2];
  auto loadK = [&](int m0k) {
#pragma unroll
    for (int t = 0; t < 2; ++t) {
      int c = tid + t * 256;
      int row = c >> 3, hc = c & 7;
      int tok = m0k + row;
      bf16x8 val = z8;
      if (hc < 6 && tok < NTOK)
        val = *(const bf16x8*)(qk + (tokbase + tok) * (2 * CH) + CH + h * HDIM + hc * 8);
      kreg[t] = val;
    }
  };
  auto loadV = [&](int m0k) {
#pragma unroll
    for (int t = 0; t < 2; ++t) {
      int c = tid + t * 256;
      if (c < HDIM * 8) {
        int d = c >> 3, hc = c & 7;
        vreg[t] = *(const bf16x8*)(vt + (size_t)(h * HDIM + d) * VT_CSTRIDE + b * VT_BSTRIDE + m0k + hc * 8);
      }
    }
  };

  float m_i[2][4], l_i[2][4];
#pragma unroll
  for (int s = 0; s < 2; ++s)
#pragma unroll
    for (int r = 0; r < 4; ++r) { m_i[s][r] = -1e30f; l_i[s][r] = 0.f; }
  f32x4 o[2][3];
  const f32x4 zf = {0.f, 0.f, 0.f, 0.f};
#pragma unroll
  for (int s = 0; s < 2; ++s)
#pragma unroll
    for (int t = 0; t < 3; ++t) o[s][t] = zf;

  loadK(0);
  loadV(0);

  for (int m0 = 0; m0 < NTOK; m0 += KTL) {
    __syncthreads();
#pragma unroll
    for (int t = 0; t < 2; ++t) {
      int c = tid + t * 256;
      *(bf16x8*)&Ks[c >> 3][(c & 7) * 8] = kreg[t];
    }
#pragma unroll
    for (int t = 0; t < 2; ++t) {
      int c = tid + t * 256;
      if (c < HDIM * 8) *(bf16x8*)&Vts[c >> 3][(c & 7) * 8] = vreg[t];
    }
    __syncthreads();
    int mn = m0 + KTL;
    if (mn < NTOK) { loadK(mn); loadV(mn); }

    f32x4 sa[2][4];
#pragma unroll
    for (int s = 0; s < 2; ++s)
#pragma unroll
      for (int j = 0; j < 4; ++j) sa[s][j] = zf;
#pragma unroll
    for (int kk = 0; kk < 2; ++kk) {
#pragma unroll
      for (int j = 0; j < 4; ++j) {
        bf16x8 kf = *(const bf16x8*)&Ks[j * 16 + l16][kk * 32 + quad * 8];
        sa[0][j] = __builtin_amdgcn_mfma_f32_16x16x32_bf16(aq[0][kk], kf, sa[0][j], 0, 0, 0);
        sa[1][j] = __builtin_amdgcn_mfma_f32_16x16x32_bf16(aq[1][kk], kf, sa[1][j], 0, 0, 0);
      }
    }

    const bool lastT = (m0 + KTL > NTOK);
    float alpha[2][4];
#pragma unroll
    for (int s = 0; s < 2; ++s) {
#pragma unroll
      for (int r = 0; r < 4; ++r) {
        float sv0 = sa[s][0][r], sv1 = sa[s][1][r], sv2 = sa[s][2][r], sv3 = sa[s][3][r];
        if (lastT) {
          if (m0 + 0 * 16 + l16 >= NTOK) sv0 = -1e30f;
          if (m0 + 1 * 16 + l16 >= NTOK) sv1 = -1e30f;
          if (m0 + 2 * 16 + l16 >= NTOK) sv2 = -1e30f;
          if (m0 + 3 * 16 + l16 >= NTOK) sv3 = -1e30f;
        }
        float mx = fmaxf(fmaxf(sv0, sv1), fmaxf(sv2, sv3));
#pragma unroll
        for (int off = 1; off < 16; off <<= 1) mx = fmaxf(mx, __shfl_xor(mx, off, 16));
        float mnew = fmaxf(m_i[s][r], mx);
        float al = __builtin_amdgcn_exp2f(m_i[s][r] - mnew);
        alpha[s][r] = al;
        m_i[s][r] = mnew;
        float p0 = __builtin_amdgcn_exp2f(sv0 - mnew);
        float p1 = __builtin_amdgcn_exp2f(sv1 - mnew);
        float p2 = __builtin_amdgcn_exp2f(sv2 - mnew);
        float p3 = __builtin_amdgcn_exp2f(sv3 - mnew);
        float sum = (p0 + p1) + (p2 + p3);
        int prow = s * 16 + quad * 4 + r;
        Ps[w][prow][4 * l16 + 0] = f2bf_bits(p0);
        Ps[w][prow][4 * l16 + 1] = f2bf_bits(p1);
        Ps[w][prow][4 * l16 + 2] = f2bf_bits(p2);
        Ps[w][prow][4 * l16 + 3] = f2bf_bits(p3);
#pragma unroll
        for (int off = 1; off < 16; off <<= 1) sum += __shfl_xor(sum, off, 16);
        l_i[s][r] = l_i[s][r] * al + sum;
      }
    }
#pragma unroll
    for (int s = 0; s < 2; ++s)
#pragma unroll
      for (int t = 0; t < 3; ++t)
#pragma unroll
        for (int r = 0; r < 4; ++r) o[s][t][r] *= alpha[s][r];

    __syncthreads();  // LDS fence: all P writes retired before any P read

    bf16x8 pf[2][2];
#pragma unroll
    for (int s = 0; s < 2; ++s)
#pragma unroll
      for (int kk = 0; kk < 2; ++kk)
        pf[s][kk] = *(const bf16x8*)&Ps[w][s * 16 + l16][kk * 32 + quad * 8];
#pragma unroll
    for (int kk = 0; kk < 2; ++kk) {
#pragma unroll
      for (int t = 0; t < 3; ++t) {
        bf16x8 vf = *(const bf16x8*)&Vts[t * 16 + l16][kk * 32 + quad * 8];
        o[0][t] = __builtin_amdgcn_mfma_f32_16x16x32_bf16(pf[0][kk], vf, o[0][t], 0, 0, 0);
        o[1][t] = __builtin_amdgcn_mfma_f32_16x16x32_bf16(pf[1][kk], vf, o[1][t], 0, 0, 0);
      }
    }
  }

#pragma unroll
  for (int s = 0; s < 2; ++s) {
    float inv[4];
#pragma unroll
    for (int r = 0; r < 4; ++r) inv[r] = __builtin_amdgcn_rcpf(l_i[s][r]);
#pragma unroll
    for (int t = 0; t < 3; ++t) {
#pragma unroll
      for (int r = 0; r < 4; ++r) {
        int tok = n0 + w * 32 + s * 16 + quad * 4 + r;
        if (tok < NTOK)
          ob[(tokbase + tok) * CH + h * HDIM + t * 16 + l16] =
              __float2bfloat16(o[s][t][r] * inv[r]);
      }
    }
  }
}

// ---------------- launch -----------------------------------------------------
extern "C" void kernel_launch(void* const* d_in, const int* in_sizes, int n_in,
                              void* d_out, int out_size, void* d_ws, size_t ws_size,
                              hipStream_t stream) {
  const float* x       = (const float*)d_in[0];
  const float* local_w = (const float*)d_in[1];
  const float* local_b = (const float*)d_in[2];
  const float* bn1_g   = (const float*)d_in[3];
  const float* bn1_b   = (const float*)d_in[4];
  const float* bn1_m   = (const float*)d_in[5];
  const float* bn1_v   = (const float*)d_in[6];
  const float* q_w     = (const float*)d_in[7];
  const float* q_b     = (const float*)d_in[8];
  const float* k_w     = (const float*)d_in[9];
  const float* k_b     = (const float*)d_in[10];
  const float* v_w     = (const float*)d_in[11];
  const float* v_b     = (const float*)d_in[12];
  const float* proj_w  = (const float*)d_in[13];
  const float* proj_b  = (const float*)d_in[14];
  const float* ffn1_w  = (const float*)d_in[15];
  const float* ffn1_b  = (const float*)d_in[16];
  const float* ffn2_w  = (const float*)d_in[17];
  const float* ffn2_b  = (const float*)d_in[18];
  const float* bn2_g   = (const float*)d_in[19];
  const float* bn2_b   = (const float*)d_in[20];
  const float* bn2_m   = (const float*)d_in[21];
  const float* bn2_v   = (const float*)d_in[22];

  char* wsb = (char*)d_ws;
  __hip_bfloat16* lx_cmb  = (__hip_bfloat16*)(wsb + 0);          // 9.6 MB, dead after transpose
  __hip_bfloat16* gelu_a  = (__hip_bfloat16*)(wsb + 0);          // 38.5 MB (clobbers lx_cmb+qk)
  __hip_bfloat16* qk_act  = (__hip_bfloat16*)(wsb + 19267584);   // 19.3 MB, dead after attention
  __hip_bfloat16* attn_a  = (__hip_bfloat16*)(wsb + 48168960);
  __hip_bfloat16* lx_tm   = (__hip_bfloat16*)(wsb + 57802752);
  __hip_bfloat16* resid_a = (__hip_bfloat16*)(wsb + 67436544);
  __hip_bfloat16* w_qkv   = (__hip_bfloat16*)(wsb + 77070336);   // contiguous:
  __hip_bfloat16* w_proj  = (__hip_bfloat16*)(wsb + 77955072);   //  qkv|proj|
  __hip_bfloat16* w_ffn1  = (__hip_bfloat16*)(wsb + 78249984);   //  ffn1|ffn2
  __hip_bfloat16* w_ffn2  = (__hip_bfloat16*)(wsb + 79429632);
  float*          b_qkv   = (float*)(wsb + 80609280);
  float*          b_ffn1  = (float*)(wsb + 80613888);
  __hip_bfloat16* vt      = (__hip_bfloat16*)(wsb + 85000192);   // own region, 10.2 MB

  // 1. merged prep (weights, biases, ffn1-bias fold, vt tail zero)
  cvt_all<<<dim3((NW_ALL + 255) / 256), dim3(256), 0, stream>>>(
      q_w, k_w, v_w, proj_w, ffn1_w, ffn2_w, bn2_g, bn2_v, q_b, k_b, v_b,
      ffn1_b, bn2_b, bn2_m, w_qkv, b_qkv, b_ffn1, vt);

  // 2-3. depthwise conv (bf16 out) + transpose to token-major
  dwconv_bn<<<dim3(BATCH * CH), dim3(256), 0, stream>>>(
      x, local_w, local_b, bn1_g, bn1_b, bn1_m, bn1_v, lx_cmb);
  transpose_b<<<dim3(25, 12, BATCH), dim3(256), 0, stream>>>(
      (const ushort*)lx_cmb, (ushort*)lx_tm);

  // 4. fused QKV GEMM -> qk_act [tok][768] + vt (phi-permuted V^T)
  gemm_mfma<0, 128, 128><<<dim3(QKVC / 128, NTOT / 128), dim3(256), 0, stream>>>(
      lx_tm, w_qkv, b_qkv, nullptr, qk_act, vt, CH);

  // 5. attention
  attention_mfma2<<<dim3((NTOK + QTL - 1) / QTL, NHEADS, BATCH), dim3(256), 0, stream>>>(
      qk_act, vt, attn_a);

  // 6. proj + lx residual (128x64 tiles -> 588 blocks, was 294)
  gemm_mfma<1, 128, 64><<<dim3(CH / 64, NTOT / 128), dim3(256), 0, stream>>>(
      attn_a, w_proj, proj_b, lx_tm, resid_a, nullptr, CH);

  // 7. ffn1 (BN2 folded) + GELU
  gemm_mfma<2, 128, 128><<<dim3(C4 / 128, NTOT / 128), dim3(256), 0, stream>>>(
      resid_a, w_ffn1, b_ffn1, nullptr, gelu_a, nullptr, CH);

  // 8. ffn2 + residual -> fp32 channel-major output (64x128 tiles -> 588 blocks)
  gemm_mfma<3, 64, 128><<<dim3(NTOT / 128, CH / 64), dim3(256), 0, stream>>>(
      w_ffn2, gelu_a, ffn2_b, resid_a, d_out, nullptr, C4);
}